// Round 7
// baseline (443.699 us; speedup 1.0000x reference)
//
// MongeGapTransport: KNN gather + 5-layer MLP pushforward, bf16 I/O (confirmed).
// R22: counter-driven round. R21 instrumentation proved:
//  - gram K-loop = 16-19us, MfmaUtil 29%, VALUBusy 48%, 1.7e7 LDS bank conflicts
//    (stride-40 tile => 4-way conflict on ds_read_b128; fl=1 staging is VALU-heavy).
//  - hidden-GEMM K-loop = 5-8us (R17-R20 schedule attempts were correctly null).
// R22 changes:
//  1. gram fl=1 path rebuilt on the gemm-proven structure: gl2lds16 staging into
//     stride-32 [128][32] tiles, 16 MFMA/wave/K-step, 4 steps. Conflicts -> ~0,
//     VALU staging -> 0. (fl=0 keeps old path for dtype robustness.)
//  2. INSTRUMENT knn x8 (gemm_knn_k visible if knn>5.4us) and prep x4 (visible
//     if prep>10.7us) to locate the remaining ~100us. Strip next round.
#include <hip/hip_runtime.h>
#include <hip/hip_fp16.h>
#include <stdint.h>

typedef unsigned short u16;
typedef unsigned int   u32;
typedef unsigned long long u64;
typedef short v8bf __attribute__((ext_vector_type(8)));
typedef float v4f  __attribute__((ext_vector_type(4)));
typedef u16   v8u  __attribute__((ext_vector_type(8)));

#define NPTS 4096
#define DF   128
#define DR   64
#define HID  1024
#define KNN  10
#define DIN  192

#define KNN_REPS  8
#define PREP_REPS 4

#define AS1 __attribute__((address_space(1)))
#define AS3 __attribute__((address_space(3)))

__device__ __forceinline__ float bf2f(u16 b){ return __uint_as_float(((unsigned)b)<<16); }
__device__ __forceinline__ u16 f2bf(float f){
  unsigned u = __float_as_uint(f);
  unsigned r = 0x7fffu + ((u>>16)&1u);
  return (u16)((u + r)>>16);
}
__device__ __forceinline__ u16 f2h(float f){
  __half h = __float2half(f);           // RN, monotone
  return __half_as_ushort(h);
}
__device__ __forceinline__ float softplus_f(float x){
  return x>15.f ? x : __logf(1.f + __expf(x));
}
__device__ __forceinline__ float rdv(const void* p, long j, int fl){
  return fl ? bf2f(((const u16*)p)[j]) : ((const float*)p)[j];
}
__device__ __forceinline__ void gl2lds16(const u16* g, u16* l){
  __builtin_amdgcn_global_load_lds((const AS1 unsigned int*)g, (AS3 unsigned int*)l, 16, 0, 0);
}

// ---------- dtype detection (R2-proven) ----------
__global__ void detect_k(const u16* __restrict__ c, int* __restrict__ flag){
  __shared__ int cnt[256];
  int t = threadIdx.x, n = 0;
  for(int i=t; i<8192; i+=256){
    u16 v = c[2*i];
    int e = (v>>7)&0xff;
    n += (e>=96 && e<=158);
  }
  cnt[t] = n; __syncthreads();
  for(int s=128; s>0; s>>=1){ if(t<s) cnt[t]+=cnt[t+s]; __syncthreads(); }
  if(t==0) *flag = (cnt[0] > 4915) ? 1 : 0;
}

// ---------- fused prep: cvt | weight transposes | sqnorm(raw) | buildx(raw) ----------
// INSTRUMENTED: whole body x PREP_REPS (idempotent; barrier between reps).
__global__ void prep_k(const void* cond, const void* tens,
    const void* Wi, const void* W1, const void* W2, const void* W3, const void* Wo,
    const void* bi, const void* b1, const void* b2, const void* b3, const void* bo,
    float* __restrict__ condF, float* __restrict__ tensF, float* __restrict__ biasF,
    u16* Oi, u16* O1, u16* O2, u16* O3, u16* Oo,
    float* __restrict__ sq, u16* __restrict__ X, const int* __restrict__ flag){
  __shared__ u16 tile[32][33];
  const int fl = *flag;
  const int bid = blockIdx.x, tid = threadIdx.x;
  for(int rep=0; rep<PREP_REPS; ++rep){
  if(bid < 3089){
    int i = bid*256 + tid;
    if(i < 524288){ condF[i] = rdv(cond, i, fl); }
    else if(i < 786432){ tensF[i-524288] = rdv(tens, i-524288, fl); }
    else{
      int j = i - 786432;
      if(j < 1024)      biasF[j] = rdv(bi, j, fl);
      else if(j < 2048) biasF[j] = rdv(b1, j-1024, fl);
      else if(j < 3072) biasF[j] = rdv(b2, j-2048, fl);
      else if(j < 4096) biasF[j] = rdv(b3, j-3072, fl);
      else if(j < 4160) biasF[j] = rdv(bo, j-4096, fl);
    }
  } else if(bid < 6417){
    int b = bid - 3089;
    const void* in; u16* out; int R, C, bx, by;
    if(b < 192)      {              in=Wi; out=Oi; R=192;  C=1024; bx=b&31; by=b>>5; }
    else if(b < 1216){ b -= 192;    in=W1; out=O1; R=1024; C=1024; bx=b&31; by=b>>5; }
    else if(b < 2240){ b -= 1216;   in=W2; out=O2; R=1024; C=1024; bx=b&31; by=b>>5; }
    else if(b < 3264){ b -= 2240;   in=W3; out=O3; R=1024; C=1024; bx=b&31; by=b>>5; }
    else             { b -= 3264;   in=Wo; out=Oo; R=1024; C=64;   bx=b&1;  by=b>>1; }
    int gx = bx*32, gy = by*32;
    int tx = tid&31, ty = tid>>5;
    #pragma unroll
    for(int r=ty; r<32; r+=8){
      size_t idx = (size_t)(gy+r)*C + gx + tx;
      tile[r][tx] = fl ? ((const u16*)in)[idx] : f2bf(((const float*)in)[idx]);
    }
    __syncthreads();
    #pragma unroll
    for(int r=ty; r<32; r+=8) out[(size_t)(gx+r)*R + gy + tx] = tile[tx][r];
  } else if(bid < 7441){
    int b = bid - 6417;
    int row = b*4 + (tid>>6), lane = tid&63;
    float a = rdv(cond, (long)row*DF + lane, fl);
    float c2 = rdv(cond, (long)row*DF + lane + 64, fl);
    double s = (double)a*a + (double)c2*c2;
    #pragma unroll
    for(int off=32; off>0; off>>=1) s += __shfl_down(s, off, 64);
    if(lane==0) sq[row] = (float)s;
  } else {
    int c = (bid-7441)*256 + tid;
    int j = c/48;
    int off = (c - j*48)*4;
    ushort4 o;
    if(off < DF){
      o.x = f2bf(rdv(cond, (long)j*DF + off + 0, fl));
      o.y = f2bf(rdv(cond, (long)j*DF + off + 1, fl));
      o.z = f2bf(rdv(cond, (long)j*DF + off + 2, fl));
      o.w = f2bf(rdv(cond, (long)j*DF + off + 3, fl));
    }else{
      int t2 = off - DF;
      o.x = f2bf(rdv(tens, (long)j*DR + t2 + 0, fl));
      o.y = f2bf(rdv(tens, (long)j*DR + t2 + 1, fl));
      o.z = f2bf(rdv(tens, (long)j*DR + t2 + 2, fl));
      o.w = f2bf(rdv(tens, (long)j*DR + t2 + 3, fl));
    }
    *(ushort4*)&X[(size_t)j*DIN + off] = o;
  }
  __syncthreads();   // rep separator (tile WAR + keeps stores live per rep)
  }
}

// ---------- hidden-layer GEMM body: 128x64 tile, BK=64 (R18-proven) ----------
__device__ __forceinline__ void gemm_bt_body(const u16* __restrict__ A,
    const u16* __restrict__ Bt, const float* __restrict__ bias, u16* __restrict__ C,
    int Nc, int Kc, int bid, u16* As, u16* Bs){
  const int xcd = bid&7, slot = bid>>3;
  const int bm = (xcd*4 + (slot>>4)) * 128;
  const int bn = (slot&15) * 64;
  const int tid = threadIdx.x, lane = tid&63, wave = tid>>6;
  const int wm = (wave&1)*64, wn = (wave>>1)*32;
  int c0 = wave*128 + lane, c1 = c0 + 64;
  int r0 = c0>>2, q0 = c0&3, r1 = c1>>2, q1 = c1&3;
  int cb = wave*64 + lane, rb = cb>>2, qb = cb&3;
  const u16* pA0 = A  + (size_t)(bm+r0)*Kc + q0*8;
  const u16* pA1 = A  + (size_t)(bm+r1)*Kc + q1*8;
  const u16* pB  = Bt + (size_t)(bn+rb)*Kc + qb*8;
  u16* lA0 = &As[wave*1024];
  u16* lA1 = &As[wave*1024 + 512];
  u16* lB  = &Bs[wave*512];
  const int m16 = lane&15, q = lane>>4;
  v4f acc[4][2] = {};
  for(int kb=0; kb<Kc; kb+=64){
    gl2lds16(pA0 + kb, lA0);
    gl2lds16(pA1 + kb, lA1);
    gl2lds16(pB  + kb, lB);
    gl2lds16(pA0 + kb + 32, lA0 + 4096);
    gl2lds16(pA1 + kb + 32, lA1 + 4096);
    gl2lds16(pB  + kb + 32, lB + 2048);
    __syncthreads();
    #pragma unroll
    for(int kk=0;kk<2;kk++){
      v8bf a[4], b[2];
      #pragma unroll
      for(int x=0;x<4;x++) a[x] = *(const v8bf*)&As[kk*4096 + (wm + x*16 + m16)*32 + q*8];
      #pragma unroll
      for(int x=0;x<2;x++) b[x] = *(const v8bf*)&Bs[kk*2048 + (wn + x*16 + m16)*32 + q*8];
      #pragma unroll
      for(int mi=0;mi<4;mi++)
        #pragma unroll
        for(int ni=0;ni<2;ni++)
          acc[mi][ni] = __builtin_amdgcn_mfma_f32_16x16x32_bf16(a[mi], b[ni], acc[mi][ni], 0,0,0);
    }
    __syncthreads();
  }
  const int col16 = lane&15, rowq = lane>>4;
  #pragma unroll
  for(int mi=0;mi<4;mi++){
    #pragma unroll
    for(int ni=0;ni<2;ni++){
      int cn = bn + wn + ni*16 + col16;
      float bi = bias[cn];
      #pragma unroll
      for(int r=0;r<4;r++){
        int rw = bm + wm + mi*16 + rowq*4 + r;
        float v = softplus_f(acc[mi][ni][r] + bi);
        C[(size_t)rw*Nc + cn] = f2bf(v);
      }
    }
  }
}

// ---------- knn body: one wave per row, fp16-key bisection on u16 bits ----------
__device__ __forceinline__ void knn_body(const u16* __restrict__ distH,
    const float* __restrict__ condF, int* __restrict__ nidx, int row,
    float* __restrict__ af, int* __restrict__ scnt,
    int* __restrict__ cand, u64* __restrict__ keys){
  const int lane = threadIdx.x&63;
  af[lane]    = condF[(size_t)row*DF + lane];
  af[lane+64] = condF[(size_t)row*DF + lane + 64];
  if(lane==0) *scnt = 0;
  const v8u* drow = (const v8u*)(distH + (size_t)row*NPTS);
  v8u vals[8];
  #pragma unroll
  for(int k=0;k<8;k++) vals[k] = drow[lane + k*64];
  u32 mx = 0;
  #pragma unroll
  for(int k=0;k<8;k++)
    #pragma unroll
    for(int e=0;e<8;e++){ u32 v = vals[k][e]; mx = v>mx ? v : mx; }
  #pragma unroll
  for(int off=32; off>0; off>>=1){
    u32 o = (u32)__shfl_down((int)mx, off, 64); mx = o>mx ? o : mx;
  }
  mx = (u32)__shfl((int)mx, 0, 64);
  u32 hi = mx+1, lo = 0;
  for(int it=0; it<17; ++it){
    u32 mid = (lo+hi)>>1;
    int c = 0;
    #pragma unroll
    for(int k=0;k<8;k++)
      #pragma unroll
      for(int e=0;e<8;e++) c += ((u32)vals[k][e] < mid);
    #pragma unroll
    for(int off=32; off>0; off>>=1) c += __shfl_down(c, off, 64);
    c = __shfl(c, 0, 64);
    if(c >= 16){ hi = mid; if(c <= 48) break; }
    else lo = mid;
  }
  const u32 t = hi;
  #pragma unroll
  for(int k=0;k<8;k++)
    #pragma unroll
    for(int e=0;e<8;e++){
      if((u32)vals[k][e] < t){
        int s = atomicAdd(scnt, 1);
        if(s < 64) cand[s] = (lane + k*64)*8 + e;
      }
    }
  // same-wave LDS ordering: all atomics precede this read in program order.
  int cnt = *scnt; if(cnt > 64) cnt = 64;
  u64 mykey = ~0ULL; int myj = -1;
  if(lane < cnt){
    int j = cand[lane];
    const float4* bp4 = (const float4*)(condF + (size_t)j*DF);
    double s = 0.0;
    #pragma unroll
    for(int v4i=0; v4i<32; v4i++){
      float4 bv = bp4[v4i];
      double d0 = (double)af[v4i*4+0]-(double)bv.x;
      double d1 = (double)af[v4i*4+1]-(double)bv.y;
      double d2 = (double)af[v4i*4+2]-(double)bv.z;
      double d3 = (double)af[v4i*4+3]-(double)bv.w;
      s += d0*d0 + d1*d1 + d2*d2 + d3*d3;
    }
    u64 bits = (u64)__double_as_longlong(s);
    mykey = (bits & ~0xFFFULL) | (u32)j;
    myj = j;
  }
  keys[lane] = mykey;
  if(lane < cnt){
    int rank = 0;
    for(int c2=0;c2<cnt;c2++) rank += (keys[c2] < mykey);
    if(rank < KNN) nidx[row*KNN + rank] = myj;
  }
}

// ---------- fused: gemm1 (blocks 0..511, K=192) || gram->fp16 d^2 (blocks 512..1535) ----------
// fl=1 gram: gl2lds stride-32 staging (gemm-proven, conflict-free), 16 MFMA/wave/step.
__global__ __launch_bounds__(256,2) void gram_g1_k(const u16* __restrict__ condB,
    const float* __restrict__ condF, const float* __restrict__ sq,
    u16* __restrict__ distH, const int* __restrict__ flag,
    const u16* __restrict__ X, const u16* __restrict__ Wt_in,
    const float* __restrict__ biasF, u16* __restrict__ A0){
  __shared__ __align__(16) u16 smem[20480];
  const int bid = blockIdx.x;
  if(bid < 512){
    gemm_bt_body(X, Wt_in, biasF, A0, HID, DIN, bid, smem, smem+8192);
    return;
  }
  const int gb = bid - 512;
  const int fl = *flag;
  const int bm = (gb&31)*128, bn = (gb>>5)*128;
  const int tid = threadIdx.x, lane = tid&63, wave = tid>>6;
  const int wm = (wave&1)*64, wn = (wave>>1)*64;
  const int m16 = lane&15, q = lane>>4;
  v4f acc[4][4] = {};
  if(fl){
    // ---- fast path: gl2lds16, As=smem[0..4096), Bs=smem[4096..8192), stride 32 ----
    const int srow = wave*32 + (lane>>2), scol = (lane&3)*8;
    const u16* gA = condB + (size_t)(bm+srow)*DF + scol;
    const u16* gB = condB + (size_t)(bn+srow)*DF + scol;
    u16* lA = &smem[wave*1024];
    u16* lB = &smem[4096 + wave*1024];
    for(int kb=0; kb<DF; kb+=32){
      gl2lds16(gA + kb,                 lA);
      gl2lds16(gA + kb + (size_t)16*DF, lA + 512);
      gl2lds16(gB + kb,                 lB);
      gl2lds16(gB + kb + (size_t)16*DF, lB + 512);
      __syncthreads();
      v8bf a[4], b[4];
      #pragma unroll
      for(int x=0;x<4;x++){
        a[x] = *(const v8bf*)&smem[(wm + x*16 + m16)*32 + q*8];
        b[x] = *(const v8bf*)&smem[4096 + (wn + x*16 + m16)*32 + q*8];
      }
      #pragma unroll
      for(int mi=0;mi<4;mi++)
        #pragma unroll
        for(int ni=0;ni<4;ni++)
          acc[mi][ni] = __builtin_amdgcn_mfma_f32_16x16x32_bf16(a[mi], b[ni], acc[mi][ni], 0,0,0);
      __syncthreads();
    }
  } else {
    // ---- fp32-input path (correctness; not the hot dtype): old hi/lo split ----
    u16* Ahi = smem;
    u16* Alo = smem + 5120;
    u16* Bhi = smem + 10240;
    u16* Blo = smem + 15360;
    for(int kb=0; kb<DF; kb+=32){
      #pragma unroll
      for(int t=0;t<4;t++){
        int ch = tid + t*256;
        int r = ch>>3, c = (ch&7)*4;
        float4 av = *(const float4*)&condF[(size_t)(bm+r)*DF + kb + c];
        float4 bv = *(const float4*)&condF[(size_t)(bn+r)*DF + kb + c];
        ushort4 ah, bh, al, bl;
        ah.x=f2bf(av.x); ah.y=f2bf(av.y); ah.z=f2bf(av.z); ah.w=f2bf(av.w);
        bh.x=f2bf(bv.x); bh.y=f2bf(bv.y); bh.z=f2bf(bv.z); bh.w=f2bf(bv.w);
        al.x=f2bf(av.x-bf2f(ah.x)); al.y=f2bf(av.y-bf2f(ah.y));
        al.z=f2bf(av.z-bf2f(ah.z)); al.w=f2bf(av.w-bf2f(ah.w));
        bl.x=f2bf(bv.x-bf2f(bh.x)); bl.y=f2bf(bv.y-bf2f(bh.y));
        bl.z=f2bf(bv.z-bf2f(bh.z)); bl.w=f2bf(bv.w-bf2f(bh.w));
        *(ushort4*)&Ahi[r*40+c] = ah; *(ushort4*)&Bhi[r*40+c] = bh;
        *(ushort4*)&Alo[r*40+c] = al; *(ushort4*)&Blo[r*40+c] = bl;
      }
      __syncthreads();
      v8bf ahf[4], bhf[4], alf[4], blf[4];
      #pragma unroll
      for(int x=0;x<4;x++){
        ahf[x] = *(const v8bf*)&Ahi[(wm + x*16 + m16)*40 + q*8];
        bhf[x] = *(const v8bf*)&Bhi[(wn + x*16 + m16)*40 + q*8];
        alf[x] = *(const v8bf*)&Alo[(wm + x*16 + m16)*40 + q*8];
        blf[x] = *(const v8bf*)&Blo[(wn + x*16 + m16)*40 + q*8];
      }
      #pragma unroll
      for(int mi=0;mi<4;mi++)
        #pragma unroll
        for(int ni=0;ni<4;ni++){
          acc[mi][ni] = __builtin_amdgcn_mfma_f32_16x16x32_bf16(alf[mi], bhf[ni], acc[mi][ni], 0,0,0);
          acc[mi][ni] = __builtin_amdgcn_mfma_f32_16x16x32_bf16(ahf[mi], blf[ni], acc[mi][ni], 0,0,0);
          acc[mi][ni] = __builtin_amdgcn_mfma_f32_16x16x32_bf16(ahf[mi], bhf[ni], acc[mi][ni], 0,0,0);
        }
      __syncthreads();
    }
  }
  const int col16 = lane&15, rowq = lane>>4;
  #pragma unroll
  for(int mi=0;mi<4;mi++){
    #pragma unroll
    for(int ni=0;ni<4;ni++){
      int cj = bn + wn + ni*16 + col16;
      float sqj = sq[cj];
      #pragma unroll
      for(int r=0;r<4;r++){
        int ri = bm + wm + mi*16 + rowq*4 + r;
        float d2 = (sq[ri] + sqj) - 2.0f*acc[mi][ni][r];
        distH[(size_t)ri*NPTS + cj] = f2h(fmaxf(d2, 0.f));
      }
    }
  }
}

// ---------- fused: hidden GEMM (blocks 0..511) || knn half x8 (blocks 512..1023) ----------
__global__ __launch_bounds__(256,2) void gemm_knn_k(const u16* __restrict__ A,
    const u16* __restrict__ Bt, const float* __restrict__ bias, u16* __restrict__ C,
    const u16* __restrict__ distH, const float* __restrict__ condF,
    int* __restrict__ nidx, int rowoff){
  __shared__ __align__(16) u16 gsm[12288];
  __shared__ float af[4][DF];
  __shared__ int   scnt[4];
  __shared__ int   cand[4][64];
  __shared__ u64   keys[4][64];
  const int bid = blockIdx.x;
  if(bid < 512){
    gemm_bt_body(A, Bt, bias, C, HID, HID, bid, gsm, gsm+8192);
  } else {
    const int wv = threadIdx.x>>6;
    const int row = rowoff + (bid-512)*4 + wv;
    for(int rep=0; rep<KNN_REPS; ++rep)     // INSTRUMENTATION: x8, idempotent
      knn_body(distH, condF, nidx, row, af[wv], &scnt[wv], cand[wv], keys[wv]);
  }
}

// ---------- standalone hidden GEMM (layer 4) ----------
__global__ __launch_bounds__(256,2) void gemm_bt_k(const u16* __restrict__ A,
    const u16* __restrict__ Bt, const float* __restrict__ bias, u16* __restrict__ C){
  __shared__ __align__(16) u16 As[8192];
  __shared__ __align__(16) u16 Bs[4096];
  gemm_bt_body(A, Bt, bias, C, HID, HID, blockIdx.x, As, Bs);
}

// ---------- final layer, split-K=4 (R18 version) ----------
__global__ __launch_bounds__(256,2) void gemm_out_k(const u16* __restrict__ A,
    const u16* __restrict__ Bt, float* __restrict__ Pp){
  __shared__ __align__(16) u16 As[128*32];
  __shared__ __align__(16) u16 Bs[64*32];
  const int bm = (blockIdx.x>>2)*128;
  const int k0 = (blockIdx.x&3)*256;
  float* P = Pp + (size_t)(blockIdx.x&3)*262144;
  const int tid = threadIdx.x, lane = tid&63, wave = tid>>6;
  const int wm = wave*32;
  int c0 = wave*128 + lane, c1 = c0 + 64;
  int ra0 = c0>>2, qa0 = c0&3, ra1 = c1>>2, qa1 = c1&3;
  int cb = wave*64 + lane;
  int rb = cb>>2, qb = cb&3;
  const u16* pA0 = A  + (size_t)(bm+ra0)*HID + qa0*8;
  const u16* pA1 = A  + (size_t)(bm+ra1)*HID + qa1*8;
  const u16* pB  = Bt + (size_t)rb*HID + qb*8;
  u16* lA0 = &As[(wave*128     )*8];
  u16* lA1 = &As[(wave*128 + 64)*8];
  u16* lB  = &Bs[(wave*64      )*8];
  const int m16 = lane&15, q = lane>>4;
  v4f acc[2][4] = {};
  for(int kb=k0; kb<k0+256; kb+=32){
    gl2lds16(pA0 + kb, lA0);
    gl2lds16(pA1 + kb, lA1);
    gl2lds16(pB  + kb, lB);
    __syncthreads();
    v8bf a[2], b[4];
    a[0] = *(const v8bf*)&As[(wm + m16)*32 + q*8];
    a[1] = *(const v8bf*)&As[(wm + 16 + m16)*32 + q*8];
    #pragma unroll
    for(int x=0;x<4;x++) b[x] = *(const v8bf*)&Bs[(x*16 + m16)*32 + q*8];
    #pragma unroll
    for(int mi=0;mi<2;mi++)
      #pragma unroll
      for(int ni=0;ni<4;ni++)
        acc[mi][ni] = __builtin_amdgcn_mfma_f32_16x16x32_bf16(a[mi], b[ni], acc[mi][ni], 0,0,0);
    __syncthreads();
  }
  const int col16 = lane&15, rowq = lane>>4;
  #pragma unroll
  for(int mi=0;mi<2;mi++){
    #pragma unroll
    for(int ni=0;ni<4;ni++){
      int cn = ni*16 + col16;
      #pragma unroll
      for(int r=0;r<4;r++){
        int rw = bm + wm + mi*16 + rowq*4 + r;
        P[(size_t)rw*DR + cn] = acc[mi][ni][r];
      }
    }
  }
}

// ---------- gather: out[i,k,:] = tens[j] - (bias + sum_s Pp[s][j]), j=nidx ----------
__global__ void gather_k(const float* __restrict__ Pp, const float* __restrict__ tensF,
                         const float* __restrict__ biasF, const int* __restrict__ nidx,
                         void* __restrict__ outv, const int* __restrict__ flag){
  const int fl = *flag;
  int e = blockIdx.x*256 + threadIdx.x;
  int m = e>>4;
  int c = (e&15)*4;
  int j = nidx[m] & (NPTS-1);
  size_t rc = (size_t)j*DR + c;
  float4 t  = *(const float4*)&tensF[rc];
  float4 b  = *(const float4*)&biasF[4096 + c];
  float4 p0 = *(const float4*)&Pp[rc];
  float4 p1 = *(const float4*)&Pp[262144 + rc];
  float4 p2 = *(const float4*)&Pp[524288 + rc];
  float4 p3 = *(const float4*)&Pp[786432 + rc];
  float4 v;
  v.x = t.x - (b.x + ((p0.x+p1.x)+(p2.x+p3.x)));
  v.y = t.y - (b.y + ((p0.y+p1.y)+(p2.y+p3.y)));
  v.z = t.z - (b.z + ((p0.z+p1.z)+(p2.z+p3.z)));
  v.w = t.w - (b.w + ((p0.w+p1.w)+(p2.w+p3.w)));
  if(fl){
    ushort4 o; o.x=f2bf(v.x); o.y=f2bf(v.y); o.z=f2bf(v.z); o.w=f2bf(v.w);
    *(ushort4*)&((u16*)outv)[(size_t)m*DR + c] = o;
  }else{
    *(float4*)&((float*)outv)[(size_t)m*DR + c] = v;
  }
}

// ---------- workspace layout (~68 MB of 256 MiB; no aliasing) ----------
constexpr size_t OFF_FLAG  = 0;
constexpr size_t OFF_SQ    = 256;
constexpr size_t OFF_NIDX  = OFF_SQ    + 16384;
constexpr size_t OFF_BIAS  = OFF_NIDX  + 163840;
constexpr size_t OFF_CONDF = OFF_BIAS  + 16640;
constexpr size_t OFF_TENSF = OFF_CONDF + 2097152;
constexpr size_t OFF_WTIN  = OFF_TENSF + 1048576;
constexpr size_t OFF_WT1   = OFF_WTIN  + 393216;
constexpr size_t OFF_WT2   = OFF_WT1   + 2097152;
constexpr size_t OFF_WT3   = OFF_WT2   + 2097152;
constexpr size_t OFF_WTO   = OFF_WT3   + 2097152;
constexpr size_t OFF_DIST  = OFF_WTO   + 131072;
constexpr size_t OFF_X     = OFF_DIST  + 33554432;   // fp16 dist
constexpr size_t OFF_A0    = OFF_X     + 1572864;
constexpr size_t OFF_A1    = OFF_A0    + 8388608;
constexpr size_t OFF_P     = OFF_A1    + 8388608;    // 4 x 1MB partials

extern "C" void kernel_launch(void* const* d_in, const int* in_sizes, int n_in,
                              void* d_out, int out_size, void* d_ws, size_t ws_size,
                              hipStream_t stream){
  char* ws = (char*)d_ws;
  int*   flag  = (int*)  (ws + OFF_FLAG);
  float* sqv   = (float*)(ws + OFF_SQ);
  int*   nidx  = (int*)  (ws + OFF_NIDX);
  float* biasF = (float*)(ws + OFF_BIAS);
  float* condF = (float*)(ws + OFF_CONDF);
  float* tensF = (float*)(ws + OFF_TENSF);
  u16*   Wt_in = (u16*)  (ws + OFF_WTIN);
  u16*   Wt1   = (u16*)  (ws + OFF_WT1);
  u16*   Wt2   = (u16*)  (ws + OFF_WT2);
  u16*   Wt3   = (u16*)  (ws + OFF_WT3);
  u16*   Wt_o  = (u16*)  (ws + OFF_WTO);
  u16*   distH = (u16*)  (ws + OFF_DIST);
  u16*   X     = (u16*)  (ws + OFF_X);
  u16*   A0    = (u16*)  (ws + OFF_A0);
  u16*   A1    = (u16*)  (ws + OFF_A1);
  float* Pp    = (float*)(ws + OFF_P);

  detect_k <<<1, 256, 0, stream>>>((const u16*)d_in[0], flag);
  prep_k   <<<8209, 256, 0, stream>>>(d_in[0], d_in[1],
                d_in[2], d_in[4], d_in[6], d_in[8], d_in[10],
                d_in[3], d_in[5], d_in[7], d_in[9], d_in[11],
                condF, tensF, biasF, Wt_in, Wt1, Wt2, Wt3, Wt_o, sqv, X, flag);
  // gemm1 || gram  (both depend only on prep)
  gram_g1_k<<<1536, 256, 0, stream>>>((const u16*)d_in[0], condF, sqv, distH, flag,
                                      X, Wt_in, biasF, A0);
  // gemm2 || knn rows 0..2047
  gemm_knn_k<<<1024, 256, 0, stream>>>(A0, Wt1, biasF+1024, A1, distH, condF, nidx, 0);
  // gemm3 || knn rows 2048..4095
  gemm_knn_k<<<1024, 256, 0, stream>>>(A1, Wt2, biasF+2048, A0, distH, condF, nidx, 2048);
  gemm_bt_k  <<<512, 256, 0, stream>>>(A0, Wt3, biasF+3072, A1);
  gemm_out_k <<<128, 256, 0, stream>>>(A1, Wt_o, Pp);
  gather_k   <<<2560, 256, 0, stream>>>(Pp, tensF, biasF, nidx, d_out, flag);
}

// Round 8
// 210.510 us; speedup vs baseline: 2.1077x; 2.1077x over previous
//
// MongeGapTransport: KNN gather + 5-layer MLP pushforward, bf16 I/O (confirmed).
// R23: counter-driven. R21/R22 instrumentation ledger:
//  - gram K-loop 16-19us (fixed in R22: stride-32 gl2lds staging, conflicts->0)
//  - hidden GEMM K-loop 5-8us each (schedule attempts correctly null)
//  - knn = 17.6us/half (x8 rows, R22) -- THE dominant kernel phase (~35-40us).
//    VALUBusy 38%, HBM 3%: serial-latency-bound on 17x(64 cmp + 6-deep shfl
//    reduce + broadcast) + 64 divergent LDS atomics.
//  - prep <= ~35us (x4 never surfaced above 141us rows).
// R23: instrumentation stripped; knn counting rebuilt wave-collective:
//  - count via __popcll(__ballot(v<mid)): v_cmp->SALU bcnt/add, count lands
//    uniform in SGPR; shfl chain AND broadcast gone (SALU overlaps VALU).
//  - early-exit window 16<=c<=64 (cand capacity).
//  - compaction via ballot+prefix (popcll(mask&below)) + uniform base; no atomics.
#include <hip/hip_runtime.h>
#include <hip/hip_fp16.h>
#include <stdint.h>

typedef unsigned short u16;
typedef unsigned int   u32;
typedef unsigned long long u64;
typedef short v8bf __attribute__((ext_vector_type(8)));
typedef float v4f  __attribute__((ext_vector_type(4)));
typedef u16   v8u  __attribute__((ext_vector_type(8)));

#define NPTS 4096
#define DF   128
#define DR   64
#define HID  1024
#define KNN  10
#define DIN  192

#define AS1 __attribute__((address_space(1)))
#define AS3 __attribute__((address_space(3)))

__device__ __forceinline__ float bf2f(u16 b){ return __uint_as_float(((unsigned)b)<<16); }
__device__ __forceinline__ u16 f2bf(float f){
  unsigned u = __float_as_uint(f);
  unsigned r = 0x7fffu + ((u>>16)&1u);
  return (u16)((u + r)>>16);
}
__device__ __forceinline__ u16 f2h(float f){
  __half h = __float2half(f);           // RN, monotone
  return __half_as_ushort(h);
}
__device__ __forceinline__ float softplus_f(float x){
  return x>15.f ? x : __logf(1.f + __expf(x));
}
__device__ __forceinline__ float rdv(const void* p, long j, int fl){
  return fl ? bf2f(((const u16*)p)[j]) : ((const float*)p)[j];
}
__device__ __forceinline__ void gl2lds16(const u16* g, u16* l){
  __builtin_amdgcn_global_load_lds((const AS1 unsigned int*)g, (AS3 unsigned int*)l, 16, 0, 0);
}

// ---------- dtype detection (R2-proven) ----------
__global__ void detect_k(const u16* __restrict__ c, int* __restrict__ flag){
  __shared__ int cnt[256];
  int t = threadIdx.x, n = 0;
  for(int i=t; i<8192; i+=256){
    u16 v = c[2*i];
    int e = (v>>7)&0xff;
    n += (e>=96 && e<=158);
  }
  cnt[t] = n; __syncthreads();
  for(int s=128; s>0; s>>=1){ if(t<s) cnt[t]+=cnt[t+s]; __syncthreads(); }
  if(t==0) *flag = (cnt[0] > 4915) ? 1 : 0;
}

// ---------- fused prep: cvt | weight transposes | sqnorm(raw) | buildx(raw) ----------
__global__ void prep_k(const void* cond, const void* tens,
    const void* Wi, const void* W1, const void* W2, const void* W3, const void* Wo,
    const void* bi, const void* b1, const void* b2, const void* b3, const void* bo,
    float* __restrict__ condF, float* __restrict__ tensF, float* __restrict__ biasF,
    u16* Oi, u16* O1, u16* O2, u16* O3, u16* Oo,
    float* __restrict__ sq, u16* __restrict__ X, const int* __restrict__ flag){
  __shared__ u16 tile[32][33];
  const int fl = *flag;
  const int bid = blockIdx.x, tid = threadIdx.x;
  if(bid < 3089){
    int i = bid*256 + tid;
    if(i < 524288){ condF[i] = rdv(cond, i, fl); }
    else if(i < 786432){ tensF[i-524288] = rdv(tens, i-524288, fl); }
    else{
      int j = i - 786432;
      if(j < 1024)      biasF[j] = rdv(bi, j, fl);
      else if(j < 2048) biasF[j] = rdv(b1, j-1024, fl);
      else if(j < 3072) biasF[j] = rdv(b2, j-2048, fl);
      else if(j < 4096) biasF[j] = rdv(b3, j-3072, fl);
      else if(j < 4160) biasF[j] = rdv(bo, j-4096, fl);
    }
  } else if(bid < 6417){
    int b = bid - 3089;
    const void* in; u16* out; int R, C, bx, by;
    if(b < 192)      {              in=Wi; out=Oi; R=192;  C=1024; bx=b&31; by=b>>5; }
    else if(b < 1216){ b -= 192;    in=W1; out=O1; R=1024; C=1024; bx=b&31; by=b>>5; }
    else if(b < 2240){ b -= 1216;   in=W2; out=O2; R=1024; C=1024; bx=b&31; by=b>>5; }
    else if(b < 3264){ b -= 2240;   in=W3; out=O3; R=1024; C=1024; bx=b&31; by=b>>5; }
    else             { b -= 3264;   in=Wo; out=Oo; R=1024; C=64;   bx=b&1;  by=b>>1; }
    int gx = bx*32, gy = by*32;
    int tx = tid&31, ty = tid>>5;
    #pragma unroll
    for(int r=ty; r<32; r+=8){
      size_t idx = (size_t)(gy+r)*C + gx + tx;
      tile[r][tx] = fl ? ((const u16*)in)[idx] : f2bf(((const float*)in)[idx]);
    }
    __syncthreads();
    #pragma unroll
    for(int r=ty; r<32; r+=8) out[(size_t)(gx+r)*R + gy + tx] = tile[tx][r];
  } else if(bid < 7441){
    int b = bid - 6417;
    int row = b*4 + (tid>>6), lane = tid&63;
    float a = rdv(cond, (long)row*DF + lane, fl);
    float c2 = rdv(cond, (long)row*DF + lane + 64, fl);
    double s = (double)a*a + (double)c2*c2;
    #pragma unroll
    for(int off=32; off>0; off>>=1) s += __shfl_down(s, off, 64);
    if(lane==0) sq[row] = (float)s;
  } else {
    int c = (bid-7441)*256 + tid;
    int j = c/48;
    int off = (c - j*48)*4;
    ushort4 o;
    if(off < DF){
      o.x = f2bf(rdv(cond, (long)j*DF + off + 0, fl));
      o.y = f2bf(rdv(cond, (long)j*DF + off + 1, fl));
      o.z = f2bf(rdv(cond, (long)j*DF + off + 2, fl));
      o.w = f2bf(rdv(cond, (long)j*DF + off + 3, fl));
    }else{
      int t2 = off - DF;
      o.x = f2bf(rdv(tens, (long)j*DR + t2 + 0, fl));
      o.y = f2bf(rdv(tens, (long)j*DR + t2 + 1, fl));
      o.z = f2bf(rdv(tens, (long)j*DR + t2 + 2, fl));
      o.w = f2bf(rdv(tens, (long)j*DR + t2 + 3, fl));
    }
    *(ushort4*)&X[(size_t)j*DIN + off] = o;
  }
}

// ---------- hidden-layer GEMM body: 128x64 tile, BK=64 (R18-proven) ----------
__device__ __forceinline__ void gemm_bt_body(const u16* __restrict__ A,
    const u16* __restrict__ Bt, const float* __restrict__ bias, u16* __restrict__ C,
    int Nc, int Kc, int bid, u16* As, u16* Bs){
  const int xcd = bid&7, slot = bid>>3;
  const int bm = (xcd*4 + (slot>>4)) * 128;
  const int bn = (slot&15) * 64;
  const int tid = threadIdx.x, lane = tid&63, wave = tid>>6;
  const int wm = (wave&1)*64, wn = (wave>>1)*32;
  int c0 = wave*128 + lane, c1 = c0 + 64;
  int r0 = c0>>2, q0 = c0&3, r1 = c1>>2, q1 = c1&3;
  int cb = wave*64 + lane, rb = cb>>2, qb = cb&3;
  const u16* pA0 = A  + (size_t)(bm+r0)*Kc + q0*8;
  const u16* pA1 = A  + (size_t)(bm+r1)*Kc + q1*8;
  const u16* pB  = Bt + (size_t)(bn+rb)*Kc + qb*8;
  u16* lA0 = &As[wave*1024];
  u16* lA1 = &As[wave*1024 + 512];
  u16* lB  = &Bs[wave*512];
  const int m16 = lane&15, q = lane>>4;
  v4f acc[4][2] = {};
  for(int kb=0; kb<Kc; kb+=64){
    gl2lds16(pA0 + kb, lA0);
    gl2lds16(pA1 + kb, lA1);
    gl2lds16(pB  + kb, lB);
    gl2lds16(pA0 + kb + 32, lA0 + 4096);
    gl2lds16(pA1 + kb + 32, lA1 + 4096);
    gl2lds16(pB  + kb + 32, lB + 2048);
    __syncthreads();
    #pragma unroll
    for(int kk=0;kk<2;kk++){
      v8bf a[4], b[2];
      #pragma unroll
      for(int x=0;x<4;x++) a[x] = *(const v8bf*)&As[kk*4096 + (wm + x*16 + m16)*32 + q*8];
      #pragma unroll
      for(int x=0;x<2;x++) b[x] = *(const v8bf*)&Bs[kk*2048 + (wn + x*16 + m16)*32 + q*8];
      #pragma unroll
      for(int mi=0;mi<4;mi++)
        #pragma unroll
        for(int ni=0;ni<2;ni++)
          acc[mi][ni] = __builtin_amdgcn_mfma_f32_16x16x32_bf16(a[mi], b[ni], acc[mi][ni], 0,0,0);
    }
    __syncthreads();
  }
  const int col16 = lane&15, rowq = lane>>4;
  #pragma unroll
  for(int mi=0;mi<4;mi++){
    #pragma unroll
    for(int ni=0;ni<2;ni++){
      int cn = bn + wn + ni*16 + col16;
      float bi = bias[cn];
      #pragma unroll
      for(int r=0;r<4;r++){
        int rw = bm + wm + mi*16 + rowq*4 + r;
        float v = softplus_f(acc[mi][ni][r] + bi);
        C[(size_t)rw*Nc + cn] = f2bf(v);
      }
    }
  }
}

// ---------- knn body: one wave per row, ballot-collective bisection ----------
// Count lands wave-uniform in SGPR via __ballot+popcount (no shfl, no broadcast).
// Compaction via ballot prefix (no atomics). fp16 monotone RN => exact top-10
// subset of {q(d) < t} when count(<t)>=16; fp64 refine from condF.
__device__ __forceinline__ void knn_body(const u16* __restrict__ distH,
    const float* __restrict__ condF, int* __restrict__ nidx, int row,
    float* __restrict__ af, int* __restrict__ cand, u64* __restrict__ keys){
  const int lane = threadIdx.x&63;
  af[lane]    = condF[(size_t)row*DF + lane];
  af[lane+64] = condF[(size_t)row*DF + lane + 64];
  const v8u* drow = (const v8u*)(distH + (size_t)row*NPTS);
  v8u vals[8];
  #pragma unroll
  for(int k=0;k<8;k++) vals[k] = drow[lane + k*64];
  u32 mx = 0;
  #pragma unroll
  for(int k=0;k<8;k++)
    #pragma unroll
    for(int e=0;e<8;e++){ u32 v = vals[k][e]; mx = v>mx ? v : mx; }
  #pragma unroll
  for(int off=32; off>0; off>>=1){
    u32 o = (u32)__shfl_down((int)mx, off, 64); mx = o>mx ? o : mx;
  }
  mx = (u32)__shfl((int)mx, 0, 64);
  u32 hi = mx+1, lo = 0;
  for(int it=0; it<17; ++it){
    u32 mid = (lo+hi)>>1;
    int c = 0;
    #pragma unroll
    for(int k=0;k<8;k++)
      #pragma unroll
      for(int e=0;e<8;e++)
        c += (int)__popcll(__ballot((u32)vals[k][e] < mid));
    if(c >= 16){ hi = mid; if(c <= 64) break; }
    else lo = mid;
  }
  const u32 t = hi;
  const u64 below = (1ull<<lane) - 1ull;
  int base = 0;                                   // wave-uniform (SALU)
  #pragma unroll
  for(int k=0;k<8;k++)
    #pragma unroll
    for(int e=0;e<8;e++){
      bool p = (u32)vals[k][e] < t;
      u64 m = __ballot(p);
      if(p){
        int off = base + (int)__popcll(m & below);
        if(off < 64) cand[off] = (lane + k*64)*8 + e;
      }
      base += (int)__popcll(m);
    }
  int cnt = base > 64 ? 64 : base;
  u64 mykey = ~0ULL; int myj = -1;
  if(lane < cnt){
    int j = cand[lane];
    const float4* bp4 = (const float4*)(condF + (size_t)j*DF);
    double s = 0.0;
    #pragma unroll
    for(int v4i=0; v4i<32; v4i++){
      float4 bv = bp4[v4i];
      double d0 = (double)af[v4i*4+0]-(double)bv.x;
      double d1 = (double)af[v4i*4+1]-(double)bv.y;
      double d2 = (double)af[v4i*4+2]-(double)bv.z;
      double d3 = (double)af[v4i*4+3]-(double)bv.w;
      s += d0*d0 + d1*d1 + d2*d2 + d3*d3;
    }
    u64 bits = (u64)__double_as_longlong(s);
    mykey = (bits & ~0xFFFULL) | (u32)j;
    myj = j;
  }
  keys[lane] = mykey;
  if(lane < cnt){
    int rank = 0;
    for(int c2=0;c2<cnt;c2++) rank += (keys[c2] < mykey);
    if(rank < KNN) nidx[row*KNN + rank] = myj;
  }
}

// ---------- fused: gemm1 (blocks 0..511, K=192) || gram->fp16 d^2 (blocks 512..1535) ----------
// fl=1 gram: gl2lds stride-32 staging (R22-proven fix), 16 MFMA/wave/step.
__global__ __launch_bounds__(256,2) void gram_g1_k(const u16* __restrict__ condB,
    const float* __restrict__ condF, const float* __restrict__ sq,
    u16* __restrict__ distH, const int* __restrict__ flag,
    const u16* __restrict__ X, const u16* __restrict__ Wt_in,
    const float* __restrict__ biasF, u16* __restrict__ A0){
  __shared__ __align__(16) u16 smem[20480];
  const int bid = blockIdx.x;
  if(bid < 512){
    gemm_bt_body(X, Wt_in, biasF, A0, HID, DIN, bid, smem, smem+8192);
    return;
  }
  const int gb = bid - 512;
  const int fl = *flag;
  const int bm = (gb&31)*128, bn = (gb>>5)*128;
  const int tid = threadIdx.x, lane = tid&63, wave = tid>>6;
  const int wm = (wave&1)*64, wn = (wave>>1)*64;
  const int m16 = lane&15, q = lane>>4;
  v4f acc[4][4] = {};
  if(fl){
    const int srow = wave*32 + (lane>>2), scol = (lane&3)*8;
    const u16* gA = condB + (size_t)(bm+srow)*DF + scol;
    const u16* gB = condB + (size_t)(bn+srow)*DF + scol;
    u16* lA = &smem[wave*1024];
    u16* lB = &smem[4096 + wave*1024];
    for(int kb=0; kb<DF; kb+=32){
      gl2lds16(gA + kb,                 lA);
      gl2lds16(gA + kb + (size_t)16*DF, lA + 512);
      gl2lds16(gB + kb,                 lB);
      gl2lds16(gB + kb + (size_t)16*DF, lB + 512);
      __syncthreads();
      v8bf a[4], b[4];
      #pragma unroll
      for(int x=0;x<4;x++){
        a[x] = *(const v8bf*)&smem[(wm + x*16 + m16)*32 + q*8];
        b[x] = *(const v8bf*)&smem[4096 + (wn + x*16 + m16)*32 + q*8];
      }
      #pragma unroll
      for(int mi=0;mi<4;mi++)
        #pragma unroll
        for(int ni=0;ni<4;ni++)
          acc[mi][ni] = __builtin_amdgcn_mfma_f32_16x16x32_bf16(a[mi], b[ni], acc[mi][ni], 0,0,0);
      __syncthreads();
    }
  } else {
    u16* Ahi = smem;
    u16* Alo = smem + 5120;
    u16* Bhi = smem + 10240;
    u16* Blo = smem + 15360;
    for(int kb=0; kb<DF; kb+=32){
      #pragma unroll
      for(int t=0;t<4;t++){
        int ch = tid + t*256;
        int r = ch>>3, c = (ch&7)*4;
        float4 av = *(const float4*)&condF[(size_t)(bm+r)*DF + kb + c];
        float4 bv = *(const float4*)&condF[(size_t)(bn+r)*DF + kb + c];
        ushort4 ah, bh, al, bl;
        ah.x=f2bf(av.x); ah.y=f2bf(av.y); ah.z=f2bf(av.z); ah.w=f2bf(av.w);
        bh.x=f2bf(bv.x); bh.y=f2bf(bv.y); bh.z=f2bf(bv.z); bh.w=f2bf(bv.w);
        al.x=f2bf(av.x-bf2f(ah.x)); al.y=f2bf(av.y-bf2f(ah.y));
        al.z=f2bf(av.z-bf2f(ah.z)); al.w=f2bf(av.w-bf2f(ah.w));
        bl.x=f2bf(bv.x-bf2f(bh.x)); bl.y=f2bf(bv.y-bf2f(bh.y));
        bl.z=f2bf(bv.z-bf2f(bh.z)); bl.w=f2bf(bv.w-bf2f(bh.w));
        *(ushort4*)&Ahi[r*40+c] = ah; *(ushort4*)&Bhi[r*40+c] = bh;
        *(ushort4*)&Alo[r*40+c] = al; *(ushort4*)&Blo[r*40+c] = bl;
      }
      __syncthreads();
      v8bf ahf[4], bhf[4], alf[4], blf[4];
      #pragma unroll
      for(int x=0;x<4;x++){
        ahf[x] = *(const v8bf*)&Ahi[(wm + x*16 + m16)*40 + q*8];
        bhf[x] = *(const v8bf*)&Bhi[(wn + x*16 + m16)*40 + q*8];
        alf[x] = *(const v8bf*)&Alo[(wm + x*16 + m16)*40 + q*8];
        blf[x] = *(const v8bf*)&Blo[(wn + x*16 + m16)*40 + q*8];
      }
      #pragma unroll
      for(int mi=0;mi<4;mi++)
        #pragma unroll
        for(int ni=0;ni<4;ni++){
          acc[mi][ni] = __builtin_amdgcn_mfma_f32_16x16x32_bf16(alf[mi], bhf[ni], acc[mi][ni], 0,0,0);
          acc[mi][ni] = __builtin_amdgcn_mfma_f32_16x16x32_bf16(ahf[mi], blf[ni], acc[mi][ni], 0,0,0);
          acc[mi][ni] = __builtin_amdgcn_mfma_f32_16x16x32_bf16(ahf[mi], bhf[ni], acc[mi][ni], 0,0,0);
        }
      __syncthreads();
    }
  }
  const int col16 = lane&15, rowq = lane>>4;
  #pragma unroll
  for(int mi=0;mi<4;mi++){
    #pragma unroll
    for(int ni=0;ni<4;ni++){
      int cj = bn + wn + ni*16 + col16;
      float sqj = sq[cj];
      #pragma unroll
      for(int r=0;r<4;r++){
        int ri = bm + wm + mi*16 + rowq*4 + r;
        float d2 = (sq[ri] + sqj) - 2.0f*acc[mi][ni][r];
        distH[(size_t)ri*NPTS + cj] = f2h(fmaxf(d2, 0.f));
      }
    }
  }
}

// ---------- fused: hidden GEMM (blocks 0..511) || knn half (blocks 512..1023) ----------
__global__ __launch_bounds__(256,2) void gemm_knn_k(const u16* __restrict__ A,
    const u16* __restrict__ Bt, const float* __restrict__ bias, u16* __restrict__ C,
    const u16* __restrict__ distH, const float* __restrict__ condF,
    int* __restrict__ nidx, int rowoff){
  __shared__ __align__(16) u16 gsm[12288];
  __shared__ float af[4][DF];
  __shared__ int   cand[4][64];
  __shared__ u64   keys[4][64];
  const int bid = blockIdx.x;
  if(bid < 512){
    gemm_bt_body(A, Bt, bias, C, HID, HID, bid, gsm, gsm+8192);
  } else {
    const int wv = threadIdx.x>>6;
    const int row = rowoff + (bid-512)*4 + wv;
    knn_body(distH, condF, nidx, row, af[wv], cand[wv], keys[wv]);
  }
}

// ---------- standalone hidden GEMM (layer 4) ----------
__global__ __launch_bounds__(256,2) void gemm_bt_k(const u16* __restrict__ A,
    const u16* __restrict__ Bt, const float* __restrict__ bias, u16* __restrict__ C){
  __shared__ __align__(16) u16 As[8192];
  __shared__ __align__(16) u16 Bs[4096];
  gemm_bt_body(A, Bt, bias, C, HID, HID, blockIdx.x, As, Bs);
}

// ---------- final layer, split-K=4 (R18 version) ----------
__global__ __launch_bounds__(256,2) void gemm_out_k(const u16* __restrict__ A,
    const u16* __restrict__ Bt, float* __restrict__ Pp){
  __shared__ __align__(16) u16 As[128*32];
  __shared__ __align__(16) u16 Bs[64*32];
  const int bm = (blockIdx.x>>2)*128;
  const int k0 = (blockIdx.x&3)*256;
  float* P = Pp + (size_t)(blockIdx.x&3)*262144;
  const int tid = threadIdx.x, lane = tid&63, wave = tid>>6;
  const int wm = wave*32;
  int c0 = wave*128 + lane, c1 = c0 + 64;
  int ra0 = c0>>2, qa0 = c0&3, ra1 = c1>>2, qa1 = c1&3;
  int cb = wave*64 + lane;
  int rb = cb>>2, qb = cb&3;
  const u16* pA0 = A  + (size_t)(bm+ra0)*HID + qa0*8;
  const u16* pA1 = A  + (size_t)(bm+ra1)*HID + qa1*8;
  const u16* pB  = Bt + (size_t)rb*HID + qb*8;
  u16* lA0 = &As[(wave*128     )*8];
  u16* lA1 = &As[(wave*128 + 64)*8];
  u16* lB  = &Bs[(wave*64      )*8];
  const int m16 = lane&15, q = lane>>4;
  v4f acc[2][4] = {};
  for(int kb=k0; kb<k0+256; kb+=32){
    gl2lds16(pA0 + kb, lA0);
    gl2lds16(pA1 + kb, lA1);
    gl2lds16(pB  + kb, lB);
    __syncthreads();
    v8bf a[2], b[4];
    a[0] = *(const v8bf*)&As[(wm + m16)*32 + q*8];
    a[1] = *(const v8bf*)&As[(wm + 16 + m16)*32 + q*8];
    #pragma unroll
    for(int x=0;x<4;x++) b[x] = *(const v8bf*)&Bs[(x*16 + m16)*32 + q*8];
    #pragma unroll
    for(int mi=0;mi<2;mi++)
      #pragma unroll
      for(int ni=0;ni<4;ni++)
        acc[mi][ni] = __builtin_amdgcn_mfma_f32_16x16x32_bf16(a[mi], b[ni], acc[mi][ni], 0,0,0);
    __syncthreads();
  }
  const int col16 = lane&15, rowq = lane>>4;
  #pragma unroll
  for(int mi=0;mi<2;mi++){
    #pragma unroll
    for(int ni=0;ni<4;ni++){
      int cn = ni*16 + col16;
      #pragma unroll
      for(int r=0;r<4;r++){
        int rw = bm + wm + mi*16 + rowq*4 + r;
        P[(size_t)rw*DR + cn] = acc[mi][ni][r];
      }
    }
  }
}

// ---------- gather: out[i,k,:] = tens[j] - (bias + sum_s Pp[s][j]), j=nidx ----------
__global__ void gather_k(const float* __restrict__ Pp, const float* __restrict__ tensF,
                         const float* __restrict__ biasF, const int* __restrict__ nidx,
                         void* __restrict__ outv, const int* __restrict__ flag){
  const int fl = *flag;
  int e = blockIdx.x*256 + threadIdx.x;
  int m = e>>4;
  int c = (e&15)*4;
  int j = nidx[m] & (NPTS-1);
  size_t rc = (size_t)j*DR + c;
  float4 t  = *(const float4*)&tensF[rc];
  float4 b  = *(const float4*)&biasF[4096 + c];
  float4 p0 = *(const float4*)&Pp[rc];
  float4 p1 = *(const float4*)&Pp[262144 + rc];
  float4 p2 = *(const float4*)&Pp[524288 + rc];
  float4 p3 = *(const float4*)&Pp[786432 + rc];
  float4 v;
  v.x = t.x - (b.x + ((p0.x+p1.x)+(p2.x+p3.x)));
  v.y = t.y - (b.y + ((p0.y+p1.y)+(p2.y+p3.y)));
  v.z = t.z - (b.z + ((p0.z+p1.z)+(p2.z+p3.z)));
  v.w = t.w - (b.w + ((p0.w+p1.w)+(p2.w+p3.w)));
  if(fl){
    ushort4 o; o.x=f2bf(v.x); o.y=f2bf(v.y); o.z=f2bf(v.z); o.w=f2bf(v.w);
    *(ushort4*)&((u16*)outv)[(size_t)m*DR + c] = o;
  }else{
    *(float4*)&((float*)outv)[(size_t)m*DR + c] = v;
  }
}

// ---------- workspace layout (~68 MB of 256 MiB; no aliasing) ----------
constexpr size_t OFF_FLAG  = 0;
constexpr size_t OFF_SQ    = 256;
constexpr size_t OFF_NIDX  = OFF_SQ    + 16384;
constexpr size_t OFF_BIAS  = OFF_NIDX  + 163840;
constexpr size_t OFF_CONDF = OFF_BIAS  + 16640;
constexpr size_t OFF_TENSF = OFF_CONDF + 2097152;
constexpr size_t OFF_WTIN  = OFF_TENSF + 1048576;
constexpr size_t OFF_WT1   = OFF_WTIN  + 393216;
constexpr size_t OFF_WT2   = OFF_WT1   + 2097152;
constexpr size_t OFF_WT3   = OFF_WT2   + 2097152;
constexpr size_t OFF_WTO   = OFF_WT3   + 2097152;
constexpr size_t OFF_DIST  = OFF_WTO   + 131072;
constexpr size_t OFF_X     = OFF_DIST  + 33554432;   // fp16 dist
constexpr size_t OFF_A0    = OFF_X     + 1572864;
constexpr size_t OFF_A1    = OFF_A0    + 8388608;
constexpr size_t OFF_P     = OFF_A1    + 8388608;    // 4 x 1MB partials

extern "C" void kernel_launch(void* const* d_in, const int* in_sizes, int n_in,
                              void* d_out, int out_size, void* d_ws, size_t ws_size,
                              hipStream_t stream){
  char* ws = (char*)d_ws;
  int*   flag  = (int*)  (ws + OFF_FLAG);
  float* sqv   = (float*)(ws + OFF_SQ);
  int*   nidx  = (int*)  (ws + OFF_NIDX);
  float* biasF = (float*)(ws + OFF_BIAS);
  float* condF = (float*)(ws + OFF_CONDF);
  float* tensF = (float*)(ws + OFF_TENSF);
  u16*   Wt_in = (u16*)  (ws + OFF_WTIN);
  u16*   Wt1   = (u16*)  (ws + OFF_WT1);
  u16*   Wt2   = (u16*)  (ws + OFF_WT2);
  u16*   Wt3   = (u16*)  (ws + OFF_WT3);
  u16*   Wt_o  = (u16*)  (ws + OFF_WTO);
  u16*   distH = (u16*)  (ws + OFF_DIST);
  u16*   X     = (u16*)  (ws + OFF_X);
  u16*   A0    = (u16*)  (ws + OFF_A0);
  u16*   A1    = (u16*)  (ws + OFF_A1);
  float* Pp    = (float*)(ws + OFF_P);

  detect_k <<<1, 256, 0, stream>>>((const u16*)d_in[0], flag);
  prep_k   <<<8209, 256, 0, stream>>>(d_in[0], d_in[1],
                d_in[2], d_in[4], d_in[6], d_in[8], d_in[10],
                d_in[3], d_in[5], d_in[7], d_in[9], d_in[11],
                condF, tensF, biasF, Wt_in, Wt1, Wt2, Wt3, Wt_o, sqv, X, flag);
  // gemm1 || gram  (both depend only on prep)
  gram_g1_k<<<1536, 256, 0, stream>>>((const u16*)d_in[0], condF, sqv, distH, flag,
                                      X, Wt_in, biasF, A0);
  // gemm2 || knn rows 0..2047
  gemm_knn_k<<<1024, 256, 0, stream>>>(A0, Wt1, biasF+1024, A1, distH, condF, nidx, 0);
  // gemm3 || knn rows 2048..4095
  gemm_knn_k<<<1024, 256, 0, stream>>>(A1, Wt2, biasF+2048, A0, distH, condF, nidx, 2048);
  gemm_bt_k  <<<512, 256, 0, stream>>>(A0, Wt3, biasF+3072, A1);
  gemm_out_k <<<128, 256, 0, stream>>>(A1, Wt_o, Pp);
  gather_k   <<<2560, 256, 0, stream>>>(Pp, tensF, biasF, nidx, d_out, flag);
}

// Round 10
// 206.599 us; speedup vs baseline: 2.1476x; 1.0189x over previous
//
// MongeGapTransport: KNN gather + 5-layer MLP pushforward, bf16 I/O (confirmed).
// R25: single-kernel fusion, de-risked after R24's container failure.
//  - R24 used hipLaunchCooperativeKernel; container died twice (suspect: capture
//    interaction or residency deadlock). R25 uses a PLAIN <<<512,256>>> launch +
//    hand-rolled epoch grid-barrier (device-scope atomics + threadfence), which
//    is graph-capturable. Barrier words zeroed via 64B hipMemsetAsync (captured).
//  - Host occupancy guard: if mega_k can't fit 2 blocks/CU (512 co-resident),
//    fall back to the PROVEN R23 8-kernel path (210.5us) instead of deadlocking.
//  - Phase bodies byte-identical to R23 (R18 GEMM, R22 gram, R23 ballot-knn).
// Ledger motivation: measured phase work ~87-110us vs 210us total => ~12us/launch
// x 9; fusing to 1-2 dispatches should recover most of it.
#include <hip/hip_runtime.h>
#include <hip/hip_fp16.h>
#include <stdint.h>

typedef unsigned short u16;
typedef unsigned int   u32;
typedef unsigned long long u64;
typedef short v8bf __attribute__((ext_vector_type(8)));
typedef float v4f  __attribute__((ext_vector_type(4)));
typedef u16   v8u  __attribute__((ext_vector_type(8)));

#define NPTS 4096
#define DF   128
#define DR   64
#define HID  1024
#define KNN  10
#define DIN  192
#define NB   512   // mega grid size (2 blocks/CU on 256 CUs)

#define AS1 __attribute__((address_space(1)))
#define AS3 __attribute__((address_space(3)))

__device__ __forceinline__ float bf2f(u16 b){ return __uint_as_float(((unsigned)b)<<16); }
__device__ __forceinline__ u16 f2bf(float f){
  unsigned u = __float_as_uint(f);
  unsigned r = 0x7fffu + ((u>>16)&1u);
  return (u16)((u + r)>>16);
}
__device__ __forceinline__ u16 f2h(float f){
  __half h = __float2half(f);           // RN, monotone
  return __half_as_ushort(h);
}
__device__ __forceinline__ float softplus_f(float x){
  return x>15.f ? x : __logf(1.f + __expf(x));
}
__device__ __forceinline__ float rdv(const void* p, long j, int fl){
  return fl ? bf2f(((const u16*)p)[j]) : ((const float*)p)[j];
}
__device__ __forceinline__ void gl2lds16(const u16* g, u16* l){
  __builtin_amdgcn_global_load_lds((const AS1 unsigned int*)g, (AS3 unsigned int*)l, 16, 0, 0);
}

// ---------- workspace layout ----------
constexpr size_t OFF_BAR   = 0;      // 2x u32 barrier (cnt, rel) -- memset to 0
constexpr size_t OFF_FLAG  = 128;    // dtype flag (fallback path)
constexpr size_t OFF_SQ    = 256;
constexpr size_t OFF_NIDX  = OFF_SQ    + 16384;
constexpr size_t OFF_BIAS  = OFF_NIDX  + 163840;
constexpr size_t OFF_CONDF = OFF_BIAS  + 16640;
constexpr size_t OFF_TENSF = OFF_CONDF + 2097152;
constexpr size_t OFF_WTIN  = OFF_TENSF + 1048576;
constexpr size_t OFF_WT1   = OFF_WTIN  + 393216;
constexpr size_t OFF_WT2   = OFF_WT1   + 2097152;
constexpr size_t OFF_WT3   = OFF_WT2   + 2097152;
constexpr size_t OFF_WTO   = OFF_WT3   + 2097152;
constexpr size_t OFF_DIST  = OFF_WTO   + 131072;
constexpr size_t OFF_X     = OFF_DIST  + 33554432;   // fp16 dist
constexpr size_t OFF_A0    = OFF_X     + 1572864;
constexpr size_t OFF_A1    = OFF_A0    + 8388608;
constexpr size_t OFF_P     = OFF_A1    + 8388608;    // 4 x 1MB partials

// ---------- hand-rolled epoch grid barrier (device-scope) ----------
__device__ __forceinline__ void gbar(u32* cnt, u32* rel, u32 e){
  __syncthreads();
  if(threadIdx.x == 0){
    __threadfence();   // release prior writes device-wide (cross-XCD)
    u32 a = __hip_atomic_fetch_add(cnt, 1u, __ATOMIC_ACQ_REL, __HIP_MEMORY_SCOPE_AGENT);
    if(a == e*NB + (NB-1)){
      __hip_atomic_store(rel, e+1u, __ATOMIC_RELEASE, __HIP_MEMORY_SCOPE_AGENT);
    } else {
      while(__hip_atomic_load(rel, __ATOMIC_ACQUIRE, __HIP_MEMORY_SCOPE_AGENT) <= e)
        __builtin_amdgcn_s_sleep(2);
    }
    __threadfence();   // acquire
  }
  __syncthreads();
}

// ---------- per-block dtype detect ----------
__device__ __forceinline__ int detect_fl(const void* cond, u16* SM){
  const u16* c = (const u16*)cond;
  int tid = threadIdx.x, n = 0;
  for(int i=tid; i<8192; i+=256){
    u16 v = c[2*i];
    int e = (v>>7)&0xff;
    n += (e>=96 && e<=158);
  }
  int* cnt = (int*)SM;
  cnt[tid] = n; __syncthreads();
  for(int s=128; s>0; s>>=1){ if(tid<s) cnt[tid]+=cnt[tid+s]; __syncthreads(); }
  int fl = (cnt[0] > 4915) ? 1 : 0;
  __syncthreads();
  return fl;
}

// ---------- prep unit (R23 prep_k body, unit id u in [0,8209)) ----------
__device__ __forceinline__ void prep_unit(int u, int tid, int fl,
    const void* cond, const void* tens,
    const void* Wi, const void* W1, const void* W2, const void* W3, const void* Wo,
    const void* bi, const void* b1, const void* b2, const void* b3, const void* bo,
    float* condF, float* tensF, float* biasF,
    u16* Oi, u16* O1, u16* O2, u16* O3, u16* Oo,
    float* sq, u16* X, u16* SM){
  if(u < 3089){
    int i = u*256 + tid;
    if(i < 524288){ condF[i] = rdv(cond, i, fl); }
    else if(i < 786432){ tensF[i-524288] = rdv(tens, i-524288, fl); }
    else{
      int j = i - 786432;
      if(j < 1024)      biasF[j] = rdv(bi, j, fl);
      else if(j < 2048) biasF[j] = rdv(b1, j-1024, fl);
      else if(j < 3072) biasF[j] = rdv(b2, j-2048, fl);
      else if(j < 4096) biasF[j] = rdv(b3, j-3072, fl);
      else if(j < 4160) biasF[j] = rdv(bo, j-4096, fl);
    }
  } else if(u < 6417){
    u16 (*tile)[33] = (u16(*)[33])SM;
    int b = u - 3089;
    const void* in; u16* out; int R, C, bx, by;
    if(b < 192)      {              in=Wi; out=Oi; R=192;  C=1024; bx=b&31; by=b>>5; }
    else if(b < 1216){ b -= 192;    in=W1; out=O1; R=1024; C=1024; bx=b&31; by=b>>5; }
    else if(b < 2240){ b -= 1216;   in=W2; out=O2; R=1024; C=1024; bx=b&31; by=b>>5; }
    else if(b < 3264){ b -= 2240;   in=W3; out=O3; R=1024; C=1024; bx=b&31; by=b>>5; }
    else             { b -= 3264;   in=Wo; out=Oo; R=1024; C=64;   bx=b&1;  by=b>>1; }
    int gx = bx*32, gy = by*32;
    int tx = tid&31, ty = tid>>5;
    #pragma unroll
    for(int r=ty; r<32; r+=8){
      size_t idx = (size_t)(gy+r)*C + gx + tx;
      tile[r][tx] = fl ? ((const u16*)in)[idx] : f2bf(((const float*)in)[idx]);
    }
    __syncthreads();
    #pragma unroll
    for(int r=ty; r<32; r+=8) out[(size_t)(gx+r)*R + gy + tx] = tile[tx][r];
  } else if(u < 7441){
    int b = u - 6417;
    int row = b*4 + (tid>>6), lane = tid&63;
    float a = rdv(cond, (long)row*DF + lane, fl);
    float c2 = rdv(cond, (long)row*DF + lane + 64, fl);
    double s = (double)a*a + (double)c2*c2;
    #pragma unroll
    for(int off=32; off>0; off>>=1) s += __shfl_down(s, off, 64);
    if(lane==0) sq[row] = (float)s;
  } else {
    int c = (u-7441)*256 + tid;
    int j = c/48;
    int off = (c - j*48)*4;
    ushort4 o;
    if(off < DF){
      o.x = f2bf(rdv(cond, (long)j*DF + off + 0, fl));
      o.y = f2bf(rdv(cond, (long)j*DF + off + 1, fl));
      o.z = f2bf(rdv(cond, (long)j*DF + off + 2, fl));
      o.w = f2bf(rdv(cond, (long)j*DF + off + 3, fl));
    }else{
      int t2 = off - DF;
      o.x = f2bf(rdv(tens, (long)j*DR + t2 + 0, fl));
      o.y = f2bf(rdv(tens, (long)j*DR + t2 + 1, fl));
      o.z = f2bf(rdv(tens, (long)j*DR + t2 + 2, fl));
      o.w = f2bf(rdv(tens, (long)j*DR + t2 + 3, fl));
    }
    *(ushort4*)&X[(size_t)j*DIN + off] = o;
  }
}

// ---------- hidden-layer GEMM body: 128x64 tile, BK=64 (R18-proven) ----------
__device__ __forceinline__ void gemm_bt_body(const u16* __restrict__ A,
    const u16* __restrict__ Bt, const float* __restrict__ bias, u16* __restrict__ C,
    int Nc, int Kc, int bid, u16* As, u16* Bs){
  const int xcd = bid&7, slot = bid>>3;
  const int bm = (xcd*4 + (slot>>4)) * 128;
  const int bn = (slot&15) * 64;
  const int tid = threadIdx.x, lane = tid&63, wave = tid>>6;
  const int wm = (wave&1)*64, wn = (wave>>1)*32;
  int c0 = wave*128 + lane, c1 = c0 + 64;
  int r0 = c0>>2, q0 = c0&3, r1 = c1>>2, q1 = c1&3;
  int cb = wave*64 + lane, rb = cb>>2, qb = cb&3;
  const u16* pA0 = A  + (size_t)(bm+r0)*Kc + q0*8;
  const u16* pA1 = A  + (size_t)(bm+r1)*Kc + q1*8;
  const u16* pB  = Bt + (size_t)(bn+rb)*Kc + qb*8;
  u16* lA0 = &As[wave*1024];
  u16* lA1 = &As[wave*1024 + 512];
  u16* lB  = &Bs[wave*512];
  const int m16 = lane&15, q = lane>>4;
  v4f acc[4][2] = {};
  for(int kb=0; kb<Kc; kb+=64){
    gl2lds16(pA0 + kb, lA0);
    gl2lds16(pA1 + kb, lA1);
    gl2lds16(pB  + kb, lB);
    gl2lds16(pA0 + kb + 32, lA0 + 4096);
    gl2lds16(pA1 + kb + 32, lA1 + 4096);
    gl2lds16(pB  + kb + 32, lB + 2048);
    __syncthreads();
    #pragma unroll
    for(int kk=0;kk<2;kk++){
      v8bf a[4], b[2];
      #pragma unroll
      for(int x=0;x<4;x++) a[x] = *(const v8bf*)&As[kk*4096 + (wm + x*16 + m16)*32 + q*8];
      #pragma unroll
      for(int x=0;x<2;x++) b[x] = *(const v8bf*)&Bs[kk*2048 + (wn + x*16 + m16)*32 + q*8];
      #pragma unroll
      for(int mi=0;mi<4;mi++)
        #pragma unroll
        for(int ni=0;ni<2;ni++)
          acc[mi][ni] = __builtin_amdgcn_mfma_f32_16x16x32_bf16(a[mi], b[ni], acc[mi][ni], 0,0,0);
    }
    __syncthreads();
  }
  const int col16 = lane&15, rowq = lane>>4;
  #pragma unroll
  for(int mi=0;mi<4;mi++){
    #pragma unroll
    for(int ni=0;ni<2;ni++){
      int cn = bn + wn + ni*16 + col16;
      float bi = bias[cn];
      #pragma unroll
      for(int r=0;r<4;r++){
        int rw = bm + wm + mi*16 + rowq*4 + r;
        float v = softplus_f(acc[mi][ni][r] + bi);
        C[(size_t)rw*Nc + cn] = f2bf(v);
      }
    }
  }
}

// ---------- knn body: one wave per row, ballot-collective bisection (R23) ----------
__device__ __forceinline__ void knn_body(const u16* __restrict__ distH,
    const float* __restrict__ condF, int* __restrict__ nidx, int row,
    float* __restrict__ af, int* __restrict__ cand, u64* __restrict__ keys){
  const int lane = threadIdx.x&63;
  af[lane]    = condF[(size_t)row*DF + lane];
  af[lane+64] = condF[(size_t)row*DF + lane + 64];
  const v8u* drow = (const v8u*)(distH + (size_t)row*NPTS);
  v8u vals[8];
  #pragma unroll
  for(int k=0;k<8;k++) vals[k] = drow[lane + k*64];
  u32 mx = 0;
  #pragma unroll
  for(int k=0;k<8;k++)
    #pragma unroll
    for(int e=0;e<8;e++){ u32 v = vals[k][e]; mx = v>mx ? v : mx; }
  #pragma unroll
  for(int off=32; off>0; off>>=1){
    u32 o = (u32)__shfl_down((int)mx, off, 64); mx = o>mx ? o : mx;
  }
  mx = (u32)__shfl((int)mx, 0, 64);
  u32 hi = mx+1, lo = 0;
  for(int it=0; it<17; ++it){
    u32 mid = (lo+hi)>>1;
    int c = 0;
    #pragma unroll
    for(int k=0;k<8;k++)
      #pragma unroll
      for(int e=0;e<8;e++)
        c += (int)__popcll(__ballot((u32)vals[k][e] < mid));
    if(c >= 16){ hi = mid; if(c <= 64) break; }
    else lo = mid;
  }
  const u32 t = hi;
  const u64 below = (1ull<<lane) - 1ull;
  int base = 0;                                   // wave-uniform
  #pragma unroll
  for(int k=0;k<8;k++)
    #pragma unroll
    for(int e=0;e<8;e++){
      bool p = (u32)vals[k][e] < t;
      u64 m = __ballot(p);
      if(p){
        int off = base + (int)__popcll(m & below);
        if(off < 64) cand[off] = (lane + k*64)*8 + e;
      }
      base += (int)__popcll(m);
    }
  int cnt = base > 64 ? 64 : base;
  u64 mykey = ~0ULL; int myj = -1;
  if(lane < cnt){
    int j = cand[lane];
    const float4* bp4 = (const float4*)(condF + (size_t)j*DF);
    double s = 0.0;
    #pragma unroll
    for(int v4i=0; v4i<32; v4i++){
      float4 bv = bp4[v4i];
      double d0 = (double)af[v4i*4+0]-(double)bv.x;
      double d1 = (double)af[v4i*4+1]-(double)bv.y;
      double d2 = (double)af[v4i*4+2]-(double)bv.z;
      double d3 = (double)af[v4i*4+3]-(double)bv.w;
      s += d0*d0 + d1*d1 + d2*d2 + d3*d3;
    }
    u64 bits = (u64)__double_as_longlong(s);
    mykey = (bits & ~0xFFFULL) | (u32)j;
    myj = j;
  }
  keys[lane] = mykey;
  if(lane < cnt){
    int rank = 0;
    for(int c2=0;c2<cnt;c2++) rank += (keys[c2] < mykey);
    if(rank < KNN) nidx[row*KNN + rank] = myj;
  }
}

// ---------- gram tile (R22-proven): fl=1 gl2lds stride-32; fl=0 hi/lo ----------
__device__ __forceinline__ void gram_tile(int gb, int fl,
    const u16* __restrict__ condB, const float* __restrict__ condF,
    const float* __restrict__ sq, u16* __restrict__ distH, u16* SM){
  const int bm = (gb&31)*128, bn = (gb>>5)*128;
  const int tid = threadIdx.x, lane = tid&63, wave = tid>>6;
  const int wm = (wave&1)*64, wn = (wave>>1)*64;
  const int m16 = lane&15, q = lane>>4;
  v4f acc[4][4] = {};
  if(fl){
    const int srow = wave*32 + (lane>>2), scol = (lane&3)*8;
    const u16* gA = condB + (size_t)(bm+srow)*DF + scol;
    const u16* gB = condB + (size_t)(bn+srow)*DF + scol;
    u16* lA = &SM[wave*1024];
    u16* lB = &SM[4096 + wave*1024];
    for(int kb=0; kb<DF; kb+=32){
      gl2lds16(gA + kb,                 lA);
      gl2lds16(gA + kb + (size_t)16*DF, lA + 512);
      gl2lds16(gB + kb,                 lB);
      gl2lds16(gB + kb + (size_t)16*DF, lB + 512);
      __syncthreads();
      v8bf a[4], b[4];
      #pragma unroll
      for(int x=0;x<4;x++){
        a[x] = *(const v8bf*)&SM[(wm + x*16 + m16)*32 + q*8];
        b[x] = *(const v8bf*)&SM[4096 + (wn + x*16 + m16)*32 + q*8];
      }
      #pragma unroll
      for(int mi=0;mi<4;mi++)
        #pragma unroll
        for(int ni=0;ni<4;ni++)
          acc[mi][ni] = __builtin_amdgcn_mfma_f32_16x16x32_bf16(a[mi], b[ni], acc[mi][ni], 0,0,0);
      __syncthreads();
    }
  } else {
    u16* Ahi = SM;
    u16* Alo = SM + 5120;
    u16* Bhi = SM + 10240;
    u16* Blo = SM + 15360;
    for(int kb=0; kb<DF; kb+=32){
      #pragma unroll
      for(int t=0;t<4;t++){
        int ch = tid + t*256;
        int r = ch>>3, c = (ch&7)*4;
        float4 av = *(const float4*)&condF[(size_t)(bm+r)*DF + kb + c];
        float4 bv = *(const float4*)&condF[(size_t)(bn+r)*DF + kb + c];
        ushort4 ah, bh, al, bl;
        ah.x=f2bf(av.x); ah.y=f2bf(av.y); ah.z=f2bf(av.z); ah.w=f2bf(av.w);
        bh.x=f2bf(bv.x); bh.y=f2bf(bv.y); bh.z=f2bf(bv.z); bh.w=f2bf(bv.w);
        al.x=f2bf(av.x-bf2f(ah.x)); al.y=f2bf(av.y-bf2f(ah.y));
        al.z=f2bf(av.z-bf2f(ah.z)); al.w=f2bf(av.w-bf2f(ah.w));
        bl.x=f2bf(bv.x-bf2f(bh.x)); bl.y=f2bf(bv.y-bf2f(bh.y));
        bl.z=f2bf(bv.z-bf2f(bh.z)); bl.w=f2bf(bv.w-bf2f(bh.w));
        *(ushort4*)&Ahi[r*40+c] = ah; *(ushort4*)&Bhi[r*40+c] = bh;
        *(ushort4*)&Alo[r*40+c] = al; *(ushort4*)&Blo[r*40+c] = bl;
      }
      __syncthreads();
      v8bf ahf[4], bhf[4], alf[4], blf[4];
      #pragma unroll
      for(int x=0;x<4;x++){
        ahf[x] = *(const v8bf*)&Ahi[(wm + x*16 + m16)*40 + q*8];
        bhf[x] = *(const v8bf*)&Bhi[(wn + x*16 + m16)*40 + q*8];
        alf[x] = *(const v8bf*)&Alo[(wm + x*16 + m16)*40 + q*8];
        blf[x] = *(const v8bf*)&Blo[(wn + x*16 + m16)*40 + q*8];
      }
      #pragma unroll
      for(int mi=0;mi<4;mi++)
        #pragma unroll
        for(int ni=0;ni<4;ni++){
          acc[mi][ni] = __builtin_amdgcn_mfma_f32_16x16x32_bf16(alf[mi], bhf[ni], acc[mi][ni], 0,0,0);
          acc[mi][ni] = __builtin_amdgcn_mfma_f32_16x16x32_bf16(ahf[mi], blf[ni], acc[mi][ni], 0,0,0);
          acc[mi][ni] = __builtin_amdgcn_mfma_f32_16x16x32_bf16(ahf[mi], bhf[ni], acc[mi][ni], 0,0,0);
        }
      __syncthreads();
    }
  }
  const int col16 = lane&15, rowq = lane>>4;
  #pragma unroll
  for(int mi=0;mi<4;mi++){
    #pragma unroll
    for(int ni=0;ni<4;ni++){
      int cj = bn + wn + ni*16 + col16;
      float sqj = sq[cj];
      #pragma unroll
      for(int r=0;r<4;r++){
        int ri = bm + wm + mi*16 + rowq*4 + r;
        float d2 = (sq[ri] + sqj) - 2.0f*acc[mi][ni][r];
        distH[(size_t)ri*NPTS + cj] = f2h(fmaxf(d2, 0.f));
      }
    }
  }
}

// ---------- final layer split-K body (R18 gemm_out, obid in [0,128)) ----------
__device__ __forceinline__ void gemm_out_body(int obid, const u16* __restrict__ A,
    const u16* __restrict__ Bt, float* __restrict__ Pp, u16* As, u16* Bs){
  const int bm = (obid>>2)*128;
  const int k0 = (obid&3)*256;
  float* P = Pp + (size_t)(obid&3)*262144;
  const int tid = threadIdx.x, lane = tid&63, wave = tid>>6;
  const int wm = wave*32;
  int c0 = wave*128 + lane, c1 = c0 + 64;
  int ra0 = c0>>2, qa0 = c0&3, ra1 = c1>>2, qa1 = c1&3;
  int cb = wave*64 + lane;
  int rb = cb>>2, qb = cb&3;
  const u16* pA0 = A  + (size_t)(bm+ra0)*HID + qa0*8;
  const u16* pA1 = A  + (size_t)(bm+ra1)*HID + qa1*8;
  const u16* pB  = Bt + (size_t)rb*HID + qb*8;
  u16* lA0 = &As[(wave*128     )*8];
  u16* lA1 = &As[(wave*128 + 64)*8];
  u16* lB  = &Bs[(wave*64      )*8];
  const int m16 = lane&15, q = lane>>4;
  v4f acc[2][4] = {};
  for(int kb=k0; kb<k0+256; kb+=32){
    gl2lds16(pA0 + kb, lA0);
    gl2lds16(pA1 + kb, lA1);
    gl2lds16(pB  + kb, lB);
    __syncthreads();
    v8bf a[2], b[4];
    a[0] = *(const v8bf*)&As[(wm + m16)*32 + q*8];
    a[1] = *(const v8bf*)&As[(wm + 16 + m16)*32 + q*8];
    #pragma unroll
    for(int x=0;x<4;x++) b[x] = *(const v8bf*)&Bs[(x*16 + m16)*32 + q*8];
    #pragma unroll
    for(int mi=0;mi<2;mi++)
      #pragma unroll
      for(int ni=0;ni<4;ni++)
        acc[mi][ni] = __builtin_amdgcn_mfma_f32_16x16x32_bf16(a[mi], b[ni], acc[mi][ni], 0,0,0);
    __syncthreads();
  }
  const int col16 = lane&15, rowq = lane>>4;
  #pragma unroll
  for(int mi=0;mi<2;mi++){
    #pragma unroll
    for(int ni=0;ni<4;ni++){
      int cn = ni*16 + col16;
      #pragma unroll
      for(int r=0;r<4;r++){
        int rw = bm + wm + mi*16 + rowq*4 + r;
        P[(size_t)rw*DR + cn] = acc[mi][ni][r];
      }
    }
  }
}

// ---------- gather unit ----------
__device__ __forceinline__ void gather_unit(int e, int fl,
    const float* Pp, const float* tensF, const float* biasF,
    const int* nidx, void* outv){
  int m = e>>4;
  int c = (e&15)*4;
  int j = nidx[m] & (NPTS-1);
  size_t rc = (size_t)j*DR + c;
  float4 t  = *(const float4*)&tensF[rc];
  float4 b  = *(const float4*)&biasF[4096 + c];
  float4 p0 = *(const float4*)&Pp[rc];
  float4 p1 = *(const float4*)&Pp[262144 + rc];
  float4 p2 = *(const float4*)&Pp[524288 + rc];
  float4 p3 = *(const float4*)&Pp[786432 + rc];
  float4 v;
  v.x = t.x - (b.x + ((p0.x+p1.x)+(p2.x+p3.x)));
  v.y = t.y - (b.y + ((p0.y+p1.y)+(p2.y+p3.y)));
  v.z = t.z - (b.z + ((p0.z+p1.z)+(p2.z+p3.z)));
  v.w = t.w - (b.w + ((p0.w+p1.w)+(p2.w+p3.w)));
  if(fl){
    ushort4 o; o.x=f2bf(v.x); o.y=f2bf(v.y); o.z=f2bf(v.z); o.w=f2bf(v.w);
    *(ushort4*)&((u16*)outv)[(size_t)m*DR + c] = o;
  }else{
    *(float4*)&((float*)outv)[(size_t)m*DR + c] = v;
  }
}

// ---------- THE mega-kernel (plain launch; hand-rolled grid barrier) ----------
__global__ void __launch_bounds__(256,2) mega_k(
    const void* cond, const void* tens,
    const void* Wi, const void* W1w, const void* W2w, const void* W3w, const void* Wow,
    const void* bi, const void* b1, const void* b2, const void* b3, const void* bo,
    char* ws, void* outv){
  __shared__ __align__(16) u16 SM[20480];   // 40KB -> 2 blocks/CU
  const int bid = blockIdx.x, tid = threadIdx.x;

  u32*   bcnt  = (u32*)  (ws + OFF_BAR);
  u32*   brel  = (u32*)  (ws + OFF_BAR + 8);
  float* sqv   = (float*)(ws + OFF_SQ);
  int*   nidx  = (int*)  (ws + OFF_NIDX);
  float* biasF = (float*)(ws + OFF_BIAS);
  float* condF = (float*)(ws + OFF_CONDF);
  float* tensF = (float*)(ws + OFF_TENSF);
  u16*   Wt_in = (u16*)  (ws + OFF_WTIN);
  u16*   Wt1   = (u16*)  (ws + OFF_WT1);
  u16*   Wt2   = (u16*)  (ws + OFF_WT2);
  u16*   Wt3   = (u16*)  (ws + OFF_WT3);
  u16*   Wt_o  = (u16*)  (ws + OFF_WTO);
  u16*   distH = (u16*)  (ws + OFF_DIST);
  u16*   X     = (u16*)  (ws + OFF_X);
  u16*   A0    = (u16*)  (ws + OFF_A0);
  u16*   A1    = (u16*)  (ws + OFF_A1);
  float* Pp    = (float*)(ws + OFF_P);

  const int fl = detect_fl(cond, SM);

  // ---- P0: prep, grid-strided ----
  for(int u=bid; u<8209; u+=NB){
    prep_unit(u, tid, fl, cond, tens, Wi, W1w, W2w, W3w, Wow, bi, b1, b2, b3, bo,
              condF, tensF, biasF, Wt_in, Wt1, Wt2, Wt3, Wt_o, sqv, X, SM);
    __syncthreads();
  }
  gbar(bcnt, brel, 0);

  // ---- P1: gemm1 (1 tile) then gram (2 tiles grid-strided) ----
  gemm_bt_body(X, Wt_in, biasF, A0, HID, DIN, bid, SM, SM+8192);
  __syncthreads();
  for(int gb=bid; gb<1024; gb+=NB){
    gram_tile(gb, fl, (const u16*)cond, condF, sqv, distH, SM);
    __syncthreads();
  }
  gbar(bcnt, brel, 1);

  // knn LDS slices (blocks 256..511 in P2-P5)
  const int wv = tid>>6;
  float* kaf  = (float*)SM + wv*128;                       // 0..2048B
  int*   kcan = (int*)((char*)SM + 2048) + wv*64;          // 2048..3072B
  u64*   kkey = (u64*)((char*)SM + 4096) + wv*64;          // 4096..6144B

  // ---- P2: gemm2 (blocks 0-255, 2 tiles) || knn rows 0..1023 ----
  if(bid < 256){
    gemm_bt_body(A0, Wt1, biasF+1024, A1, HID, HID, bid,     SM, SM+8192);
    __syncthreads();
    gemm_bt_body(A0, Wt1, biasF+1024, A1, HID, HID, bid+256, SM, SM+8192);
  } else {
    knn_body(distH, condF, nidx, (bid-256)*4 + wv, kaf, kcan, kkey);
  }
  gbar(bcnt, brel, 2);

  // ---- P3: gemm3 || knn rows 1024..2047 ----
  if(bid < 256){
    gemm_bt_body(A1, Wt2, biasF+2048, A0, HID, HID, bid,     SM, SM+8192);
    __syncthreads();
    gemm_bt_body(A1, Wt2, biasF+2048, A0, HID, HID, bid+256, SM, SM+8192);
  } else {
    knn_body(distH, condF, nidx, 1024 + (bid-256)*4 + wv, kaf, kcan, kkey);
  }
  gbar(bcnt, brel, 3);

  // ---- P4: gemm4 || knn rows 2048..3071 ----
  if(bid < 256){
    gemm_bt_body(A0, Wt3, biasF+3072, A1, HID, HID, bid,     SM, SM+8192);
    __syncthreads();
    gemm_bt_body(A0, Wt3, biasF+3072, A1, HID, HID, bid+256, SM, SM+8192);
  } else {
    knn_body(distH, condF, nidx, 2048 + (bid-256)*4 + wv, kaf, kcan, kkey);
  }
  gbar(bcnt, brel, 4);

  // ---- P5: gemm_out (blocks 0-127) || knn rows 3072..4095 ----
  if(bid < 128){
    gemm_out_body(bid, A1, Wt_o, Pp, SM, SM+8192);
  } else if(bid >= 256){
    knn_body(distH, condF, nidx, 3072 + (bid-256)*4 + wv, kaf, kcan, kkey);
  }
  gbar(bcnt, brel, 5);

  // ---- P6: gather, grid-strided ----
  for(int u=bid; u<2560; u+=NB)
    gather_unit(u*256 + tid, fl, Pp, tensF, biasF, nidx, outv);
}

// ================= fallback path: the PROVEN R23 kernels =================
__global__ void detect_k(const u16* __restrict__ c, int* __restrict__ flag){
  __shared__ int cnt[256];
  int t = threadIdx.x, n = 0;
  for(int i=t; i<8192; i+=256){
    u16 v = c[2*i];
    int e = (v>>7)&0xff;
    n += (e>=96 && e<=158);
  }
  cnt[t] = n; __syncthreads();
  for(int s=128; s>0; s>>=1){ if(t<s) cnt[t]+=cnt[t+s]; __syncthreads(); }
  if(t==0) *flag = (cnt[0] > 4915) ? 1 : 0;
}

__global__ void prep_k(const void* cond, const void* tens,
    const void* Wi, const void* W1, const void* W2, const void* W3, const void* Wo,
    const void* bi, const void* b1, const void* b2, const void* b3, const void* bo,
    float* condF, float* tensF, float* biasF,
    u16* Oi, u16* O1, u16* O2, u16* O3, u16* Oo,
    float* sq, u16* X, const int* __restrict__ flag){
  __shared__ __align__(16) u16 SM[1056];
  prep_unit(blockIdx.x, threadIdx.x, *flag, cond, tens, Wi, W1, W2, W3, Wo,
            bi, b1, b2, b3, bo, condF, tensF, biasF, Oi, O1, O2, O3, Oo, sq, X, SM);
}

__global__ __launch_bounds__(256,2) void gram_g1_k(const u16* __restrict__ condB,
    const float* __restrict__ condF, const float* __restrict__ sq,
    u16* __restrict__ distH, const int* __restrict__ flag,
    const u16* __restrict__ X, const u16* __restrict__ Wt_in,
    const float* __restrict__ biasF, u16* __restrict__ A0){
  __shared__ __align__(16) u16 SM[20480];
  const int bid = blockIdx.x;
  if(bid < 512){
    gemm_bt_body(X, Wt_in, biasF, A0, HID, DIN, bid, SM, SM+8192);
  } else {
    gram_tile(bid-512, *flag, condB, condF, sq, distH, SM);
  }
}

__global__ __launch_bounds__(256,2) void gemm_knn_k(const u16* __restrict__ A,
    const u16* __restrict__ Bt, const float* __restrict__ bias, u16* __restrict__ C,
    const u16* __restrict__ distH, const float* __restrict__ condF,
    int* __restrict__ nidx, int rowoff){
  __shared__ __align__(16) u16 gsm[12288];
  __shared__ float af[4][DF];
  __shared__ int   cand[4][64];
  __shared__ u64   keys[4][64];
  const int bid = blockIdx.x;
  if(bid < 512){
    gemm_bt_body(A, Bt, bias, C, HID, HID, bid, gsm, gsm+8192);
  } else {
    const int wv = threadIdx.x>>6;
    knn_body(distH, condF, nidx, rowoff + (bid-512)*4 + wv, af[wv], cand[wv], keys[wv]);
  }
}

__global__ __launch_bounds__(256,2) void gemm_bt_k(const u16* __restrict__ A,
    const u16* __restrict__ Bt, const float* __restrict__ bias, u16* __restrict__ C){
  __shared__ __align__(16) u16 As[8192];
  __shared__ __align__(16) u16 Bs[4096];
  gemm_bt_body(A, Bt, bias, C, HID, HID, blockIdx.x, As, Bs);
}

__global__ __launch_bounds__(256,2) void gemm_out_k(const u16* __restrict__ A,
    const u16* __restrict__ Bt, float* __restrict__ Pp){
  __shared__ __align__(16) u16 As[4096];
  __shared__ __align__(16) u16 Bs[2048];
  gemm_out_body(blockIdx.x, A, Bt, Pp, As, Bs);
}

__global__ void gather_k(const float* __restrict__ Pp, const float* __restrict__ tensF,
                         const float* __restrict__ biasF, const int* __restrict__ nidx,
                         void* __restrict__ outv, const int* __restrict__ flag){
  gather_unit(blockIdx.x*256 + threadIdx.x, *flag, Pp, tensF, biasF, nidx, outv);
}

extern "C" void kernel_launch(void* const* d_in, const int* in_sizes, int n_in,
                              void* d_out, int out_size, void* d_ws, size_t ws_size,
                              hipStream_t stream){
  char* ws = (char*)d_ws;
  int*   flag  = (int*)  (ws + OFF_FLAG);
  float* sqv   = (float*)(ws + OFF_SQ);
  int*   nidx  = (int*)  (ws + OFF_NIDX);
  float* biasF = (float*)(ws + OFF_BIAS);
  float* condF = (float*)(ws + OFF_CONDF);
  float* tensF = (float*)(ws + OFF_TENSF);
  u16*   Wt_in = (u16*)  (ws + OFF_WTIN);
  u16*   Wt1   = (u16*)  (ws + OFF_WT1);
  u16*   Wt2   = (u16*)  (ws + OFF_WT2);
  u16*   Wt3   = (u16*)  (ws + OFF_WT3);
  u16*   Wt_o  = (u16*)  (ws + OFF_WTO);
  u16*   distH = (u16*)  (ws + OFF_DIST);
  u16*   X     = (u16*)  (ws + OFF_X);
  u16*   A0    = (u16*)  (ws + OFF_A0);
  u16*   A1    = (u16*)  (ws + OFF_A1);
  float* Pp    = (float*)(ws + OFF_P);

  // Occupancy guard: mega needs 2 blocks/CU (512 co-resident) or its grid
  // barrier would deadlock. Query once; fall back to the proven R23 path.
  static int occ_cached = -1;
  if(occ_cached < 0){
    int occ = 0;
    if(hipOccupancyMaxActiveBlocksPerMultiprocessor(&occ, (const void*)mega_k, 256, 0)
       != hipSuccess) occ = 0;
    occ_cached = occ;
  }

  if(occ_cached >= 2){
    hipMemsetAsync(ws + OFF_BAR, 0, 64, stream);   // zero barrier words (captured)
    hipLaunchKernelGGL(mega_k, dim3(NB), dim3(256), 0, stream,
        d_in[0], d_in[1], d_in[2], d_in[4], d_in[6], d_in[8], d_in[10],
        d_in[3], d_in[5], d_in[7], d_in[9], d_in[11], ws, d_out);
    return;
  }

  // ---- fallback: R23 (210.5us, proven) ----
  detect_k <<<1, 256, 0, stream>>>((const u16*)d_in[0], flag);
  prep_k   <<<8209, 256, 0, stream>>>(d_in[0], d_in[1],
                d_in[2], d_in[4], d_in[6], d_in[8], d_in[10],
                d_in[3], d_in[5], d_in[7], d_in[9], d_in[11],
                condF, tensF, biasF, Wt_in, Wt1, Wt2, Wt3, Wt_o, sqv, X, flag);
  gram_g1_k<<<1536, 256, 0, stream>>>((const u16*)d_in[0], condF, sqv, distH, flag,
                                      X, Wt_in, biasF, A0);
  gemm_knn_k<<<1024, 256, 0, stream>>>(A0, Wt1, biasF+1024, A1, distH, condF, nidx, 0);
  gemm_knn_k<<<1024, 256, 0, stream>>>(A1, Wt2, biasF+2048, A0, distH, condF, nidx, 2048);
  gemm_bt_k  <<<512, 256, 0, stream>>>(A0, Wt3, biasF+3072, A1);
  gemm_out_k <<<128, 256, 0, stream>>>(A1, Wt_o, Pp);
  gather_k   <<<2560, 256, 0, stream>>>(Pp, tensF, biasF, nidx, d_out, flag);
}

// Round 11
// 205.686 us; speedup vs baseline: 2.1572x; 1.0044x over previous
//
// MongeGapTransport: KNN gather + 5-layer MLP pushforward, bf16 I/O (confirmed).
// R26: mega (R25, 206.6us) + three phase-level fixes. R25 post-mortem: fusion
// bought only 4us -> launch overhead was NOT the gap; the ~100us lives inside
// phases (marginal warm reps understate in-context cost ~2x).
//  1. knn 2-rows-per-wave ILP: interleave two independent rows per wave (the
//     per-row chain is pure serial latency: load->max->17x count->compact->
//     refine; two instances overlap pipes). All 4096 rows done by end of P3.
//  2. prep cvt path vectorized bf16x8 (was SCALAR loads, common-mistake #2):
//     3089 -> 387 units; buildx fl=1 path ushort4. prep units 8209 -> 5507.
//  3. P4 gemm4 full 512 blocks (knn finished), P5 gemm_out only.
// Occupancy guard + proven R23 fallback retained.
#include <hip/hip_runtime.h>
#include <hip/hip_fp16.h>
#include <stdint.h>

typedef unsigned short u16;
typedef unsigned int   u32;
typedef unsigned long long u64;
typedef short v8bf __attribute__((ext_vector_type(8)));
typedef float v4f  __attribute__((ext_vector_type(4)));
typedef u16   v8u  __attribute__((ext_vector_type(8)));

#define NPTS 4096
#define DF   128
#define DR   64
#define HID  1024
#define KNN  10
#define DIN  192
#define NB   512   // mega grid size (2 blocks/CU on 256 CUs)
#define PREP_UNITS 5507

#define AS1 __attribute__((address_space(1)))
#define AS3 __attribute__((address_space(3)))

__device__ __forceinline__ float bf2f(u16 b){ return __uint_as_float(((unsigned)b)<<16); }
__device__ __forceinline__ u16 f2bf(float f){
  unsigned u = __float_as_uint(f);
  unsigned r = 0x7fffu + ((u>>16)&1u);
  return (u16)((u + r)>>16);
}
__device__ __forceinline__ u16 f2h(float f){
  __half h = __float2half(f);           // RN, monotone
  return __half_as_ushort(h);
}
__device__ __forceinline__ float softplus_f(float x){
  return x>15.f ? x : __logf(1.f + __expf(x));
}
__device__ __forceinline__ float rdv(const void* p, long j, int fl){
  return fl ? bf2f(((const u16*)p)[j]) : ((const float*)p)[j];
}
__device__ __forceinline__ void gl2lds16(const u16* g, u16* l){
  __builtin_amdgcn_global_load_lds((const AS1 unsigned int*)g, (AS3 unsigned int*)l, 16, 0, 0);
}

// ---------- workspace layout ----------
constexpr size_t OFF_BAR   = 0;      // 2x u32 barrier (cnt, rel) -- memset to 0
constexpr size_t OFF_FLAG  = 128;    // dtype flag (fallback path)
constexpr size_t OFF_SQ    = 256;
constexpr size_t OFF_NIDX  = OFF_SQ    + 16384;
constexpr size_t OFF_BIAS  = OFF_NIDX  + 163840;
constexpr size_t OFF_CONDF = OFF_BIAS  + 16640;
constexpr size_t OFF_TENSF = OFF_CONDF + 2097152;
constexpr size_t OFF_WTIN  = OFF_TENSF + 1048576;
constexpr size_t OFF_WT1   = OFF_WTIN  + 393216;
constexpr size_t OFF_WT2   = OFF_WT1   + 2097152;
constexpr size_t OFF_WT3   = OFF_WT2   + 2097152;
constexpr size_t OFF_WTO   = OFF_WT3   + 2097152;
constexpr size_t OFF_DIST  = OFF_WTO   + 131072;
constexpr size_t OFF_X     = OFF_DIST  + 33554432;   // fp16 dist
constexpr size_t OFF_A0    = OFF_X     + 1572864;
constexpr size_t OFF_A1    = OFF_A0    + 8388608;
constexpr size_t OFF_P     = OFF_A1    + 8388608;    // 4 x 1MB partials

// ---------- hand-rolled epoch grid barrier (device-scope, R25-proven) ----------
__device__ __forceinline__ void gbar(u32* cnt, u32* rel, u32 e){
  __syncthreads();
  if(threadIdx.x == 0){
    __threadfence();
    u32 a = __hip_atomic_fetch_add(cnt, 1u, __ATOMIC_ACQ_REL, __HIP_MEMORY_SCOPE_AGENT);
    if(a == e*NB + (NB-1)){
      __hip_atomic_store(rel, e+1u, __ATOMIC_RELEASE, __HIP_MEMORY_SCOPE_AGENT);
    } else {
      while(__hip_atomic_load(rel, __ATOMIC_ACQUIRE, __HIP_MEMORY_SCOPE_AGENT) <= e)
        __builtin_amdgcn_s_sleep(2);
    }
    __threadfence();
  }
  __syncthreads();
}

// ---------- per-block dtype detect ----------
__device__ __forceinline__ int detect_fl(const void* cond, u16* SM){
  const u16* c = (const u16*)cond;
  int tid = threadIdx.x, n = 0;
  for(int i=tid; i<8192; i+=256){
    u16 v = c[2*i];
    int e = (v>>7)&0xff;
    n += (e>=96 && e<=158);
  }
  int* cnt = (int*)SM;
  cnt[tid] = n; __syncthreads();
  for(int s=128; s>0; s>>=1){ if(tid<s) cnt[tid]+=cnt[tid+s]; __syncthreads(); }
  int fl = (cnt[0] > 4915) ? 1 : 0;
  __syncthreads();
  return fl;
}

// ---------- vec8 convert: dst[0..8) = fp32(src[j0..j0+8)) ----------
__device__ __forceinline__ void cvt8(float* dst, const void* src, long j0, int fl){
  if(fl){
    v8u h = *(const v8u*)&((const u16*)src)[j0];
    float4 a, b;
    a.x=bf2f(h[0]); a.y=bf2f(h[1]); a.z=bf2f(h[2]); a.w=bf2f(h[3]);
    b.x=bf2f(h[4]); b.y=bf2f(h[5]); b.z=bf2f(h[6]); b.w=bf2f(h[7]);
    *(float4*)dst = a; *(float4*)(dst+4) = b;
  } else {
    *(float4*)dst     = *(const float4*)&((const float*)src)[j0];
    *(float4*)(dst+4) = *(const float4*)&((const float*)src)[j0+4];
  }
}

// ---------- prep unit (vectorized cvt; unit id u in [0,5507)) ----------
// [0,387) vec8 cvt | [387,3715) weight transpose | [3715,4739) sqnorm | [4739,5507) buildx
__device__ __forceinline__ void prep_unit(int u, int tid, int fl,
    const void* cond, const void* tens,
    const void* Wi, const void* W1, const void* W2, const void* W3, const void* Wo,
    const void* bi, const void* b1, const void* b2, const void* b3, const void* bo,
    float* condF, float* tensF, float* biasF,
    u16* Oi, u16* O1, u16* O2, u16* O3, u16* Oo,
    float* sq, u16* X, u16* SM){
  if(u < 387){
    int v = u*256 + tid;
    if(v < 65536){ cvt8(condF + (size_t)v*8, cond, (long)v*8, fl); }
    else if(v < 98304){ int w = v - 65536; cvt8(tensF + (size_t)w*8, tens, (long)w*8, fl); }
    else if(v < 98824){
      int j = (v - 98304)*8;
      const void* src; int off;
      if(j < 1024){ src=bi; off=j; }
      else if(j < 2048){ src=b1; off=j-1024; }
      else if(j < 3072){ src=b2; off=j-2048; }
      else if(j < 4096){ src=b3; off=j-3072; }
      else             { src=bo; off=j-4096; }
      cvt8(biasF + j, src, off, fl);
    }
  } else if(u < 3715){
    u16 (*tile)[33] = (u16(*)[33])SM;
    int b = u - 387;
    const void* in; u16* out; int R, C, bx, by;
    if(b < 192)      {              in=Wi; out=Oi; R=192;  C=1024; bx=b&31; by=b>>5; }
    else if(b < 1216){ b -= 192;    in=W1; out=O1; R=1024; C=1024; bx=b&31; by=b>>5; }
    else if(b < 2240){ b -= 1216;   in=W2; out=O2; R=1024; C=1024; bx=b&31; by=b>>5; }
    else if(b < 3264){ b -= 2240;   in=W3; out=O3; R=1024; C=1024; bx=b&31; by=b>>5; }
    else             { b -= 3264;   in=Wo; out=Oo; R=1024; C=64;   bx=b&1;  by=b>>1; }
    int gx = bx*32, gy = by*32;
    int tx = tid&31, ty = tid>>5;
    #pragma unroll
    for(int r=ty; r<32; r+=8){
      size_t idx = (size_t)(gy+r)*C + gx + tx;
      tile[r][tx] = fl ? ((const u16*)in)[idx] : f2bf(((const float*)in)[idx]);
    }
    __syncthreads();
    #pragma unroll
    for(int r=ty; r<32; r+=8) out[(size_t)(gx+r)*R + gy + tx] = tile[tx][r];
  } else if(u < 4739){
    int b = u - 3715;
    int row = b*4 + (tid>>6), lane = tid&63;
    float a = rdv(cond, (long)row*DF + lane, fl);
    float c2 = rdv(cond, (long)row*DF + lane + 64, fl);
    double s = (double)a*a + (double)c2*c2;
    #pragma unroll
    for(int off=32; off>0; off>>=1) s += __shfl_down(s, off, 64);
    if(lane==0) sq[row] = (float)s;
  } else {
    int c = (u-4739)*256 + tid;
    int j = c/48;
    int off = (c - j*48)*4;
    ushort4 o;
    if(fl){
      o = (off < DF) ? *(const ushort4*)&((const u16*)cond)[(size_t)j*DF + off]
                     : *(const ushort4*)&((const u16*)tens)[(size_t)j*DR + off - DF];
    } else if(off < DF){
      o.x = f2bf(((const float*)cond)[(size_t)j*DF + off + 0]);
      o.y = f2bf(((const float*)cond)[(size_t)j*DF + off + 1]);
      o.z = f2bf(((const float*)cond)[(size_t)j*DF + off + 2]);
      o.w = f2bf(((const float*)cond)[(size_t)j*DF + off + 3]);
    }else{
      int t2 = off - DF;
      o.x = f2bf(((const float*)tens)[(size_t)j*DR + t2 + 0]);
      o.y = f2bf(((const float*)tens)[(size_t)j*DR + t2 + 1]);
      o.z = f2bf(((const float*)tens)[(size_t)j*DR + t2 + 2]);
      o.w = f2bf(((const float*)tens)[(size_t)j*DR + t2 + 3]);
    }
    *(ushort4*)&X[(size_t)j*DIN + off] = o;
  }
}

// ---------- hidden-layer GEMM body: 128x64 tile, BK=64 (R18-proven) ----------
__device__ __forceinline__ void gemm_bt_body(const u16* __restrict__ A,
    const u16* __restrict__ Bt, const float* __restrict__ bias, u16* __restrict__ C,
    int Nc, int Kc, int bid, u16* As, u16* Bs){
  const int xcd = bid&7, slot = bid>>3;
  const int bm = (xcd*4 + (slot>>4)) * 128;
  const int bn = (slot&15) * 64;
  const int tid = threadIdx.x, lane = tid&63, wave = tid>>6;
  const int wm = (wave&1)*64, wn = (wave>>1)*32;
  int c0 = wave*128 + lane, c1 = c0 + 64;
  int r0 = c0>>2, q0 = c0&3, r1 = c1>>2, q1 = c1&3;
  int cb = wave*64 + lane, rb = cb>>2, qb = cb&3;
  const u16* pA0 = A  + (size_t)(bm+r0)*Kc + q0*8;
  const u16* pA1 = A  + (size_t)(bm+r1)*Kc + q1*8;
  const u16* pB  = Bt + (size_t)(bn+rb)*Kc + qb*8;
  u16* lA0 = &As[wave*1024];
  u16* lA1 = &As[wave*1024 + 512];
  u16* lB  = &Bs[wave*512];
  const int m16 = lane&15, q = lane>>4;
  v4f acc[4][2] = {};
  for(int kb=0; kb<Kc; kb+=64){
    gl2lds16(pA0 + kb, lA0);
    gl2lds16(pA1 + kb, lA1);
    gl2lds16(pB  + kb, lB);
    gl2lds16(pA0 + kb + 32, lA0 + 4096);
    gl2lds16(pA1 + kb + 32, lA1 + 4096);
    gl2lds16(pB  + kb + 32, lB + 2048);
    __syncthreads();
    #pragma unroll
    for(int kk=0;kk<2;kk++){
      v8bf a[4], b[2];
      #pragma unroll
      for(int x=0;x<4;x++) a[x] = *(const v8bf*)&As[kk*4096 + (wm + x*16 + m16)*32 + q*8];
      #pragma unroll
      for(int x=0;x<2;x++) b[x] = *(const v8bf*)&Bs[kk*2048 + (wn + x*16 + m16)*32 + q*8];
      #pragma unroll
      for(int mi=0;mi<4;mi++)
        #pragma unroll
        for(int ni=0;ni<2;ni++)
          acc[mi][ni] = __builtin_amdgcn_mfma_f32_16x16x32_bf16(a[mi], b[ni], acc[mi][ni], 0,0,0);
    }
    __syncthreads();
  }
  const int col16 = lane&15, rowq = lane>>4;
  #pragma unroll
  for(int mi=0;mi<4;mi++){
    #pragma unroll
    for(int ni=0;ni<2;ni++){
      int cn = bn + wn + ni*16 + col16;
      float bi = bias[cn];
      #pragma unroll
      for(int r=0;r<4;r++){
        int rw = bm + wm + mi*16 + rowq*4 + r;
        float v = softplus_f(acc[mi][ni][r] + bi);
        C[(size_t)rw*Nc + cn] = f2bf(v);
      }
    }
  }
}

// ---------- knn 1-row body (R23-proven; fallback path) ----------
__device__ __forceinline__ void knn_body(const u16* __restrict__ distH,
    const float* __restrict__ condF, int* __restrict__ nidx, int row,
    float* __restrict__ af, int* __restrict__ cand, u64* __restrict__ keys){
  const int lane = threadIdx.x&63;
  af[lane]    = condF[(size_t)row*DF + lane];
  af[lane+64] = condF[(size_t)row*DF + lane + 64];
  const v8u* drow = (const v8u*)(distH + (size_t)row*NPTS);
  v8u vals[8];
  #pragma unroll
  for(int k=0;k<8;k++) vals[k] = drow[lane + k*64];
  u32 mx = 0;
  #pragma unroll
  for(int k=0;k<8;k++)
    #pragma unroll
    for(int e=0;e<8;e++){ u32 v = vals[k][e]; mx = v>mx ? v : mx; }
  #pragma unroll
  for(int off=32; off>0; off>>=1){
    u32 o = (u32)__shfl_down((int)mx, off, 64); mx = o>mx ? o : mx;
  }
  mx = (u32)__shfl((int)mx, 0, 64);
  u32 hi = mx+1, lo = 0;
  for(int it=0; it<17; ++it){
    u32 mid = (lo+hi)>>1;
    int c = 0;
    #pragma unroll
    for(int k=0;k<8;k++)
      #pragma unroll
      for(int e=0;e<8;e++)
        c += (int)__popcll(__ballot((u32)vals[k][e] < mid));
    if(c >= 16){ hi = mid; if(c <= 64) break; }
    else lo = mid;
  }
  const u32 t = hi;
  const u64 below = (1ull<<lane) - 1ull;
  int base = 0;
  #pragma unroll
  for(int k=0;k<8;k++)
    #pragma unroll
    for(int e=0;e<8;e++){
      bool p = (u32)vals[k][e] < t;
      u64 m = __ballot(p);
      if(p){
        int off = base + (int)__popcll(m & below);
        if(off < 64) cand[off] = (lane + k*64)*8 + e;
      }
      base += (int)__popcll(m);
    }
  int cnt = base > 64 ? 64 : base;
  u64 mykey = ~0ULL; int myj = -1;
  if(lane < cnt){
    int j = cand[lane];
    const float4* bp4 = (const float4*)(condF + (size_t)j*DF);
    double s = 0.0;
    #pragma unroll
    for(int v4i=0; v4i<32; v4i++){
      float4 bv = bp4[v4i];
      double d0 = (double)af[v4i*4+0]-(double)bv.x;
      double d1 = (double)af[v4i*4+1]-(double)bv.y;
      double d2 = (double)af[v4i*4+2]-(double)bv.z;
      double d3 = (double)af[v4i*4+3]-(double)bv.w;
      s += d0*d0 + d1*d1 + d2*d2 + d3*d3;
    }
    u64 bits = (u64)__double_as_longlong(s);
    mykey = (bits & ~0xFFFULL) | (u32)j;
    myj = j;
  }
  keys[lane] = mykey;
  if(lane < cnt){
    int rank = 0;
    for(int c2=0;c2<cnt;c2++) rank += (keys[c2] < mykey);
    if(rank < KNN) nidx[row*KNN + rank] = myj;
  }
}

// ---------- knn 2-rows-per-wave ILP body (mega): two independent chains ----------
__device__ __forceinline__ void knn_body2(const u16* __restrict__ distH,
    const float* __restrict__ condF, int* __restrict__ nidx, int row0, int row1,
    float* af0, float* af1, int* can0, int* can1, u64* key0, u64* key1){
  const int lane = threadIdx.x&63;
  af0[lane]    = condF[(size_t)row0*DF + lane];
  af0[lane+64] = condF[(size_t)row0*DF + lane + 64];
  af1[lane]    = condF[(size_t)row1*DF + lane];
  af1[lane+64] = condF[(size_t)row1*DF + lane + 64];
  const v8u* dr0 = (const v8u*)(distH + (size_t)row0*NPTS);
  const v8u* dr1 = (const v8u*)(distH + (size_t)row1*NPTS);
  v8u v0[8], v1[8];
  #pragma unroll
  for(int k=0;k<8;k++){ v0[k] = dr0[lane + k*64]; v1[k] = dr1[lane + k*64]; }
  u32 m0 = 0, m1 = 0;
  #pragma unroll
  for(int k=0;k<8;k++)
    #pragma unroll
    for(int e=0;e<8;e++){
      u32 a = v0[k][e]; m0 = a>m0 ? a : m0;
      u32 b = v1[k][e]; m1 = b>m1 ? b : m1;
    }
  #pragma unroll
  for(int off=32; off>0; off>>=1){
    u32 a = (u32)__shfl_down((int)m0, off, 64); m0 = a>m0 ? a : m0;
    u32 b = (u32)__shfl_down((int)m1, off, 64); m1 = b>m1 ? b : m1;
  }
  m0 = (u32)__shfl((int)m0, 0, 64);
  m1 = (u32)__shfl((int)m1, 0, 64);
  u32 hi0 = m0+1, lo0 = 0, hi1 = m1+1, lo1 = 0;
  bool done0 = false, done1 = false;
  for(int it=0; it<17 && !(done0 && done1); ++it){
    u32 mid0 = (lo0+hi0)>>1, mid1 = (lo1+hi1)>>1;
    int c0 = 0, c1 = 0;
    #pragma unroll
    for(int k=0;k<8;k++)
      #pragma unroll
      for(int e=0;e<8;e++){
        c0 += ((u32)v0[k][e] < mid0);
        c1 += ((u32)v1[k][e] < mid1);
      }
    #pragma unroll
    for(int off=32; off>0; off>>=1){
      c0 += __shfl_down(c0, off, 64);
      c1 += __shfl_down(c1, off, 64);
    }
    c0 = __shfl(c0, 0, 64);
    c1 = __shfl(c1, 0, 64);
    if(!done0){ if(c0 >= 16){ hi0 = mid0; if(c0 <= 64) done0 = true; } else lo0 = mid0; }
    if(!done1){ if(c1 >= 16){ hi1 = mid1; if(c1 <= 64) done1 = true; } else lo1 = mid1; }
  }
  const u32 t0 = hi0, t1 = hi1;
  const u64 below = (1ull<<lane) - 1ull;
  int base0 = 0, base1 = 0;
  #pragma unroll
  for(int k=0;k<8;k++)
    #pragma unroll
    for(int e=0;e<8;e++){
      bool p0 = (u32)v0[k][e] < t0;
      u64 q0 = __ballot(p0);
      if(p0){
        int off = base0 + (int)__popcll(q0 & below);
        if(off < 64) can0[off] = (lane + k*64)*8 + e;
      }
      base0 += (int)__popcll(q0);
      bool p1 = (u32)v1[k][e] < t1;
      u64 q1 = __ballot(p1);
      if(p1){
        int off = base1 + (int)__popcll(q1 & below);
        if(off < 64) can1[off] = (lane + k*64)*8 + e;
      }
      base1 += (int)__popcll(q1);
    }
  int cnt0 = base0 > 64 ? 64 : base0;
  int cnt1 = base1 > 64 ? 64 : base1;
  // refine (fp64, interleaved); predicated indices -> safe row-0 loads
  int j0 = (lane < cnt0) ? can0[lane] : 0;
  int j1 = (lane < cnt1) ? can1[lane] : 0;
  const float4* p0 = (const float4*)(condF + (size_t)j0*DF);
  const float4* p1 = (const float4*)(condF + (size_t)j1*DF);
  double s0 = 0.0, s1 = 0.0;
  #pragma unroll
  for(int v4i=0; v4i<32; v4i++){
    float4 a = p0[v4i], b = p1[v4i];
    double d0 = (double)af0[v4i*4+0]-(double)a.x;
    double d1 = (double)af0[v4i*4+1]-(double)a.y;
    double d2 = (double)af0[v4i*4+2]-(double)a.z;
    double d3 = (double)af0[v4i*4+3]-(double)a.w;
    s0 += d0*d0 + d1*d1 + d2*d2 + d3*d3;
    double e0 = (double)af1[v4i*4+0]-(double)b.x;
    double e1 = (double)af1[v4i*4+1]-(double)b.y;
    double e2 = (double)af1[v4i*4+2]-(double)b.z;
    double e3 = (double)af1[v4i*4+3]-(double)b.w;
    s1 += e0*e0 + e1*e1 + e2*e2 + e3*e3;
  }
  u64 mk0 = ~0ULL, mk1 = ~0ULL;
  if(lane < cnt0) mk0 = ((u64)__double_as_longlong(s0) & ~0xFFFULL) | (u32)j0;
  if(lane < cnt1) mk1 = ((u64)__double_as_longlong(s1) & ~0xFFFULL) | (u32)j1;
  key0[lane] = mk0;
  key1[lane] = mk1;
  if(lane < cnt0){
    int rank = 0;
    for(int c2=0;c2<cnt0;c2++) rank += (key0[c2] < mk0);
    if(rank < KNN) nidx[row0*KNN + rank] = j0;
  }
  if(lane < cnt1){
    int rank = 0;
    for(int c2=0;c2<cnt1;c2++) rank += (key1[c2] < mk1);
    if(rank < KNN) nidx[row1*KNN + rank] = j1;
  }
}

// ---------- gram tile (R22-proven): fl=1 gl2lds stride-32; fl=0 hi/lo ----------
__device__ __forceinline__ void gram_tile(int gb, int fl,
    const u16* __restrict__ condB, const float* __restrict__ condF,
    const float* __restrict__ sq, u16* __restrict__ distH, u16* SM){
  const int bm = (gb&31)*128, bn = (gb>>5)*128;
  const int tid = threadIdx.x, lane = tid&63, wave = tid>>6;
  const int wm = (wave&1)*64, wn = (wave>>1)*64;
  const int m16 = lane&15, q = lane>>4;
  v4f acc[4][4] = {};
  if(fl){
    const int srow = wave*32 + (lane>>2), scol = (lane&3)*8;
    const u16* gA = condB + (size_t)(bm+srow)*DF + scol;
    const u16* gB = condB + (size_t)(bn+srow)*DF + scol;
    u16* lA = &SM[wave*1024];
    u16* lB = &SM[4096 + wave*1024];
    for(int kb=0; kb<DF; kb+=32){
      gl2lds16(gA + kb,                 lA);
      gl2lds16(gA + kb + (size_t)16*DF, lA + 512);
      gl2lds16(gB + kb,                 lB);
      gl2lds16(gB + kb + (size_t)16*DF, lB + 512);
      __syncthreads();
      v8bf a[4], b[4];
      #pragma unroll
      for(int x=0;x<4;x++){
        a[x] = *(const v8bf*)&SM[(wm + x*16 + m16)*32 + q*8];
        b[x] = *(const v8bf*)&SM[4096 + (wn + x*16 + m16)*32 + q*8];
      }
      #pragma unroll
      for(int mi=0;mi<4;mi++)
        #pragma unroll
        for(int ni=0;ni<4;ni++)
          acc[mi][ni] = __builtin_amdgcn_mfma_f32_16x16x32_bf16(a[mi], b[ni], acc[mi][ni], 0,0,0);
      __syncthreads();
    }
  } else {
    u16* Ahi = SM;
    u16* Alo = SM + 5120;
    u16* Bhi = SM + 10240;
    u16* Blo = SM + 15360;
    for(int kb=0; kb<DF; kb+=32){
      #pragma unroll
      for(int t=0;t<4;t++){
        int ch = tid + t*256;
        int r = ch>>3, c = (ch&7)*4;
        float4 av = *(const float4*)&condF[(size_t)(bm+r)*DF + kb + c];
        float4 bv = *(const float4*)&condF[(size_t)(bn+r)*DF + kb + c];
        ushort4 ah, bh, al, bl;
        ah.x=f2bf(av.x); ah.y=f2bf(av.y); ah.z=f2bf(av.z); ah.w=f2bf(av.w);
        bh.x=f2bf(bv.x); bh.y=f2bf(bv.y); bh.z=f2bf(bv.z); bh.w=f2bf(bv.w);
        al.x=f2bf(av.x-bf2f(ah.x)); al.y=f2bf(av.y-bf2f(ah.y));
        al.z=f2bf(av.z-bf2f(ah.z)); al.w=f2bf(av.w-bf2f(ah.w));
        bl.x=f2bf(bv.x-bf2f(bh.x)); bl.y=f2bf(bv.y-bf2f(bh.y));
        bl.z=f2bf(bv.z-bf2f(bh.z)); bl.w=f2bf(bv.w-bf2f(bh.w));
        *(ushort4*)&Ahi[r*40+c] = ah; *(ushort4*)&Bhi[r*40+c] = bh;
        *(ushort4*)&Alo[r*40+c] = al; *(ushort4*)&Blo[r*40+c] = bl;
      }
      __syncthreads();
      v8bf ahf[4], bhf[4], alf[4], blf[4];
      #pragma unroll
      for(int x=0;x<4;x++){
        ahf[x] = *(const v8bf*)&Ahi[(wm + x*16 + m16)*40 + q*8];
        bhf[x] = *(const v8bf*)&Bhi[(wn + x*16 + m16)*40 + q*8];
        alf[x] = *(const v8bf*)&Alo[(wm + x*16 + m16)*40 + q*8];
        blf[x] = *(const v8bf*)&Blo[(wn + x*16 + m16)*40 + q*8];
      }
      #pragma unroll
      for(int mi=0;mi<4;mi++)
        #pragma unroll
        for(int ni=0;ni<4;ni++){
          acc[mi][ni] = __builtin_amdgcn_mfma_f32_16x16x32_bf16(alf[mi], bhf[ni], acc[mi][ni], 0,0,0);
          acc[mi][ni] = __builtin_amdgcn_mfma_f32_16x16x32_bf16(ahf[mi], blf[ni], acc[mi][ni], 0,0,0);
          acc[mi][ni] = __builtin_amdgcn_mfma_f32_16x16x32_bf16(ahf[mi], bhf[ni], acc[mi][ni], 0,0,0);
        }
      __syncthreads();
    }
  }
  const int col16 = lane&15, rowq = lane>>4;
  #pragma unroll
  for(int mi=0;mi<4;mi++){
    #pragma unroll
    for(int ni=0;ni<4;ni++){
      int cj = bn + wn + ni*16 + col16;
      float sqj = sq[cj];
      #pragma unroll
      for(int r=0;r<4;r++){
        int ri = bm + wm + mi*16 + rowq*4 + r;
        float d2 = (sq[ri] + sqj) - 2.0f*acc[mi][ni][r];
        distH[(size_t)ri*NPTS + cj] = f2h(fmaxf(d2, 0.f));
      }
    }
  }
}

// ---------- final layer split-K body (R18 gemm_out, obid in [0,128)) ----------
__device__ __forceinline__ void gemm_out_body(int obid, const u16* __restrict__ A,
    const u16* __restrict__ Bt, float* __restrict__ Pp, u16* As, u16* Bs){
  const int bm = (obid>>2)*128;
  const int k0 = (obid&3)*256;
  float* P = Pp + (size_t)(obid&3)*262144;
  const int tid = threadIdx.x, lane = tid&63, wave = tid>>6;
  const int wm = wave*32;
  int c0 = wave*128 + lane, c1 = c0 + 64;
  int ra0 = c0>>2, qa0 = c0&3, ra1 = c1>>2, qa1 = c1&3;
  int cb = wave*64 + lane;
  int rb = cb>>2, qb = cb&3;
  const u16* pA0 = A  + (size_t)(bm+ra0)*HID + qa0*8;
  const u16* pA1 = A  + (size_t)(bm+ra1)*HID + qa1*8;
  const u16* pB  = Bt + (size_t)rb*HID + qb*8;
  u16* lA0 = &As[(wave*128     )*8];
  u16* lA1 = &As[(wave*128 + 64)*8];
  u16* lB  = &Bs[(wave*64      )*8];
  const int m16 = lane&15, q = lane>>4;
  v4f acc[2][4] = {};
  for(int kb=k0; kb<k0+256; kb+=32){
    gl2lds16(pA0 + kb, lA0);
    gl2lds16(pA1 + kb, lA1);
    gl2lds16(pB  + kb, lB);
    __syncthreads();
    v8bf a[2], b[4];
    a[0] = *(const v8bf*)&As[(wm + m16)*32 + q*8];
    a[1] = *(const v8bf*)&As[(wm + 16 + m16)*32 + q*8];
    #pragma unroll
    for(int x=0;x<4;x++) b[x] = *(const v8bf*)&Bs[(x*16 + m16)*32 + q*8];
    #pragma unroll
    for(int mi=0;mi<2;mi++)
      #pragma unroll
      for(int ni=0;ni<4;ni++)
        acc[mi][ni] = __builtin_amdgcn_mfma_f32_16x16x32_bf16(a[mi], b[ni], acc[mi][ni], 0,0,0);
    __syncthreads();
  }
  const int col16 = lane&15, rowq = lane>>4;
  #pragma unroll
  for(int mi=0;mi<2;mi++){
    #pragma unroll
    for(int ni=0;ni<4;ni++){
      int cn = ni*16 + col16;
      #pragma unroll
      for(int r=0;r<4;r++){
        int rw = bm + wm + mi*16 + rowq*4 + r;
        P[(size_t)rw*DR + cn] = acc[mi][ni][r];
      }
    }
  }
}

// ---------- gather unit ----------
__device__ __forceinline__ void gather_unit(int e, int fl,
    const float* Pp, const float* tensF, const float* biasF,
    const int* nidx, void* outv){
  int m = e>>4;
  int c = (e&15)*4;
  int j = nidx[m] & (NPTS-1);
  size_t rc = (size_t)j*DR + c;
  float4 t  = *(const float4*)&tensF[rc];
  float4 b  = *(const float4*)&biasF[4096 + c];
  float4 p0 = *(const float4*)&Pp[rc];
  float4 p1 = *(const float4*)&Pp[262144 + rc];
  float4 p2 = *(const float4*)&Pp[524288 + rc];
  float4 p3 = *(const float4*)&Pp[786432 + rc];
  float4 v;
  v.x = t.x - (b.x + ((p0.x+p1.x)+(p2.x+p3.x)));
  v.y = t.y - (b.y + ((p0.y+p1.y)+(p2.y+p3.y)));
  v.z = t.z - (b.z + ((p0.z+p1.z)+(p2.z+p3.z)));
  v.w = t.w - (b.w + ((p0.w+p1.w)+(p2.w+p3.w)));
  if(fl){
    ushort4 o; o.x=f2bf(v.x); o.y=f2bf(v.y); o.z=f2bf(v.z); o.w=f2bf(v.w);
    *(ushort4*)&((u16*)outv)[(size_t)m*DR + c] = o;
  }else{
    *(float4*)&((float*)outv)[(size_t)m*DR + c] = v;
  }
}

// ---------- THE mega-kernel (plain launch; hand-rolled grid barrier) ----------
__global__ void __launch_bounds__(256,2) mega_k(
    const void* cond, const void* tens,
    const void* Wi, const void* W1w, const void* W2w, const void* W3w, const void* Wow,
    const void* bi, const void* b1, const void* b2, const void* b3, const void* bo,
    char* ws, void* outv){
  __shared__ __align__(16) u16 SM[20480];   // 40KB -> 2 blocks/CU
  const int bid = blockIdx.x, tid = threadIdx.x;

  u32*   bcnt  = (u32*)  (ws + OFF_BAR);
  u32*   brel  = (u32*)  (ws + OFF_BAR + 8);
  float* sqv   = (float*)(ws + OFF_SQ);
  int*   nidx  = (int*)  (ws + OFF_NIDX);
  float* biasF = (float*)(ws + OFF_BIAS);
  float* condF = (float*)(ws + OFF_CONDF);
  float* tensF = (float*)(ws + OFF_TENSF);
  u16*   Wt_in = (u16*)  (ws + OFF_WTIN);
  u16*   Wt1   = (u16*)  (ws + OFF_WT1);
  u16*   Wt2   = (u16*)  (ws + OFF_WT2);
  u16*   Wt3   = (u16*)  (ws + OFF_WT3);
  u16*   Wt_o  = (u16*)  (ws + OFF_WTO);
  u16*   distH = (u16*)  (ws + OFF_DIST);
  u16*   X     = (u16*)  (ws + OFF_X);
  u16*   A0    = (u16*)  (ws + OFF_A0);
  u16*   A1    = (u16*)  (ws + OFF_A1);
  float* Pp    = (float*)(ws + OFF_P);

  const int fl = detect_fl(cond, SM);

  // ---- P0: prep, grid-strided ----
  for(int u=bid; u<PREP_UNITS; u+=NB){
    prep_unit(u, tid, fl, cond, tens, Wi, W1w, W2w, W3w, Wow, bi, b1, b2, b3, bo,
              condF, tensF, biasF, Wt_in, Wt1, Wt2, Wt3, Wt_o, sqv, X, SM);
    __syncthreads();
  }
  gbar(bcnt, brel, 0);

  // ---- P1: gemm1 (1 tile) then gram (2 tiles grid-strided) ----
  gemm_bt_body(X, Wt_in, biasF, A0, HID, DIN, bid, SM, SM+8192);
  __syncthreads();
  for(int gb=bid; gb<1024; gb+=NB){
    gram_tile(gb, fl, (const u16*)cond, condF, sqv, distH, SM);
    __syncthreads();
  }
  gbar(bcnt, brel, 1);

  // knn LDS slices: 8 slots (4 waves x 2 rows)
  const int wv = tid>>6;
  float* kaf0 = (float*)SM + (wv*2+0)*128;
  float* kaf1 = (float*)SM + (wv*2+1)*128;               // 0..4096B
  int*   kc0  = (int*)((char*)SM + 4096) + (wv*2+0)*64;
  int*   kc1  = (int*)((char*)SM + 4096) + (wv*2+1)*64;  // 4096..6144B
  u64*   kk0  = (u64*)((char*)SM + 8192) + (wv*2+0)*64;
  u64*   kk1  = (u64*)((char*)SM + 8192) + (wv*2+1)*64;  // 8192..12288B

  // ---- P2: gemm2 (blocks 0-255, 2 tiles) || knn rows 0..2047 (2/wave ILP) ----
  if(bid < 256){
    gemm_bt_body(A0, Wt1, biasF+1024, A1, HID, HID, bid,     SM, SM+8192);
    __syncthreads();
    gemm_bt_body(A0, Wt1, biasF+1024, A1, HID, HID, bid+256, SM, SM+8192);
  } else {
    int r0 = (bid-256)*4 + wv;
    knn_body2(distH, condF, nidx, r0, r0 + 1024, kaf0, kaf1, kc0, kc1, kk0, kk1);
  }
  gbar(bcnt, brel, 2);

  // ---- P3: gemm3 || knn rows 2048..4095 ----
  if(bid < 256){
    gemm_bt_body(A1, Wt2, biasF+2048, A0, HID, HID, bid,     SM, SM+8192);
    __syncthreads();
    gemm_bt_body(A1, Wt2, biasF+2048, A0, HID, HID, bid+256, SM, SM+8192);
  } else {
    int r0 = 2048 + (bid-256)*4 + wv;
    knn_body2(distH, condF, nidx, r0, r0 + 1024, kaf0, kaf1, kc0, kc1, kk0, kk1);
  }
  gbar(bcnt, brel, 3);

  // ---- P4: gemm4, full 512 blocks (1 tile each; knn done) ----
  gemm_bt_body(A0, Wt3, biasF+3072, A1, HID, HID, bid, SM, SM+8192);
  gbar(bcnt, brel, 4);

  // ---- P5: gemm_out (blocks 0-127, split-K=4) ----
  if(bid < 128){
    gemm_out_body(bid, A1, Wt_o, Pp, SM, SM+8192);
  }
  gbar(bcnt, brel, 5);

  // ---- P6: gather, grid-strided ----
  for(int u=bid; u<2560; u+=NB)
    gather_unit(u*256 + tid, fl, Pp, tensF, biasF, nidx, outv);
}

// ================= fallback path: the PROVEN R23 kernels =================
__global__ void detect_k(const u16* __restrict__ c, int* __restrict__ flag){
  __shared__ int cnt[256];
  int t = threadIdx.x, n = 0;
  for(int i=t; i<8192; i+=256){
    u16 v = c[2*i];
    int e = (v>>7)&0xff;
    n += (e>=96 && e<=158);
  }
  cnt[t] = n; __syncthreads();
  for(int s=128; s>0; s>>=1){ if(t<s) cnt[t]+=cnt[t+s]; __syncthreads(); }
  if(t==0) *flag = (cnt[0] > 4915) ? 1 : 0;
}

__global__ void prep_k(const void* cond, const void* tens,
    const void* Wi, const void* W1, const void* W2, const void* W3, const void* Wo,
    const void* bi, const void* b1, const void* b2, const void* b3, const void* bo,
    float* condF, float* tensF, float* biasF,
    u16* Oi, u16* O1, u16* O2, u16* O3, u16* Oo,
    float* sq, u16* X, const int* __restrict__ flag){
  __shared__ __align__(16) u16 SM[1056];
  prep_unit(blockIdx.x, threadIdx.x, *flag, cond, tens, Wi, W1, W2, W3, Wo,
            bi, b1, b2, b3, bo, condF, tensF, biasF, Oi, O1, O2, O3, Oo, sq, X, SM);
}

__global__ __launch_bounds__(256,2) void gram_g1_k(const u16* __restrict__ condB,
    const float* __restrict__ condF, const float* __restrict__ sq,
    u16* __restrict__ distH, const int* __restrict__ flag,
    const u16* __restrict__ X, const u16* __restrict__ Wt_in,
    const float* __restrict__ biasF, u16* __restrict__ A0){
  __shared__ __align__(16) u16 SM[20480];
  const int bid = blockIdx.x;
  if(bid < 512){
    gemm_bt_body(X, Wt_in, biasF, A0, HID, DIN, bid, SM, SM+8192);
  } else {
    gram_tile(bid-512, *flag, condB, condF, sq, distH, SM);
  }
}

__global__ __launch_bounds__(256,2) void gemm_knn_k(const u16* __restrict__ A,
    const u16* __restrict__ Bt, const float* __restrict__ bias, u16* __restrict__ C,
    const u16* __restrict__ distH, const float* __restrict__ condF,
    int* __restrict__ nidx, int rowoff){
  __shared__ __align__(16) u16 gsm[12288];
  __shared__ float af[4][DF];
  __shared__ int   cand[4][64];
  __shared__ u64   keys[4][64];
  const int bid = blockIdx.x;
  if(bid < 512){
    gemm_bt_body(A, Bt, bias, C, HID, HID, bid, gsm, gsm+8192);
  } else {
    const int wv = threadIdx.x>>6;
    knn_body(distH, condF, nidx, rowoff + (bid-512)*4 + wv, af[wv], cand[wv], keys[wv]);
  }
}

__global__ __launch_bounds__(256,2) void gemm_bt_k(const u16* __restrict__ A,
    const u16* __restrict__ Bt, const float* __restrict__ bias, u16* __restrict__ C){
  __shared__ __align__(16) u16 As[8192];
  __shared__ __align__(16) u16 Bs[4096];
  gemm_bt_body(A, Bt, bias, C, HID, HID, blockIdx.x, As, Bs);
}

__global__ __launch_bounds__(256,2) void gemm_out_k(const u16* __restrict__ A,
    const u16* __restrict__ Bt, float* __restrict__ Pp){
  __shared__ __align__(16) u16 As[4096];
  __shared__ __align__(16) u16 Bs[2048];
  gemm_out_body(blockIdx.x, A, Bt, Pp, As, Bs);
}

__global__ void gather_k(const float* __restrict__ Pp, const float* __restrict__ tensF,
                         const float* __restrict__ biasF, const int* __restrict__ nidx,
                         void* __restrict__ outv, const int* __restrict__ flag){
  gather_unit(blockIdx.x*256 + threadIdx.x, *flag, Pp, tensF, biasF, nidx, outv);
}

extern "C" void kernel_launch(void* const* d_in, const int* in_sizes, int n_in,
                              void* d_out, int out_size, void* d_ws, size_t ws_size,
                              hipStream_t stream){
  char* ws = (char*)d_ws;
  int*   flag  = (int*)  (ws + OFF_FLAG);
  float* sqv   = (float*)(ws + OFF_SQ);
  int*   nidx  = (int*)  (ws + OFF_NIDX);
  float* biasF = (float*)(ws + OFF_BIAS);
  float* condF = (float*)(ws + OFF_CONDF);
  float* tensF = (float*)(ws + OFF_TENSF);
  u16*   Wt_in = (u16*)  (ws + OFF_WTIN);
  u16*   Wt1   = (u16*)  (ws + OFF_WT1);
  u16*   Wt2   = (u16*)  (ws + OFF_WT2);
  u16*   Wt3   = (u16*)  (ws + OFF_WT3);
  u16*   Wt_o  = (u16*)  (ws + OFF_WTO);
  u16*   distH = (u16*)  (ws + OFF_DIST);
  u16*   X     = (u16*)  (ws + OFF_X);
  u16*   A0    = (u16*)  (ws + OFF_A0);
  u16*   A1    = (u16*)  (ws + OFF_A1);
  float* Pp    = (float*)(ws + OFF_P);

  // Occupancy guard: mega needs 2 blocks/CU (512 co-resident) or its grid
  // barrier would deadlock. Query once; fall back to the proven R23 path.
  static int occ_cached = -1;
  if(occ_cached < 0){
    int occ = 0;
    if(hipOccupancyMaxActiveBlocksPerMultiprocessor(&occ, (const void*)mega_k, 256, 0)
       != hipSuccess) occ = 0;
    occ_cached = occ;
  }

  if(occ_cached >= 2){
    hipMemsetAsync(ws + OFF_BAR, 0, 64, stream);   // zero barrier words (captured)
    hipLaunchKernelGGL(mega_k, dim3(NB), dim3(256), 0, stream,
        d_in[0], d_in[1], d_in[2], d_in[4], d_in[6], d_in[8], d_in[10],
        d_in[3], d_in[5], d_in[7], d_in[9], d_in[11], ws, d_out);
    return;
  }

  // ---- fallback: R23 structure ----
  detect_k <<<1, 256, 0, stream>>>((const u16*)d_in[0], flag);
  prep_k   <<<PREP_UNITS, 256, 0, stream>>>(d_in[0], d_in[1],
                d_in[2], d_in[4], d_in[6], d_in[8], d_in[10],
                d_in[3], d_in[5], d_in[7], d_in[9], d_in[11],
                condF, tensF, biasF, Wt_in, Wt1, Wt2, Wt3, Wt_o, sqv, X, flag);
  gram_g1_k<<<1536, 256, 0, stream>>>((const u16*)d_in[0], condF, sqv, distH, flag,
                                      X, Wt_in, biasF, A0);
  gemm_knn_k<<<1024, 256, 0, stream>>>(A0, Wt1, biasF+1024, A1, distH, condF, nidx, 0);
  gemm_knn_k<<<1024, 256, 0, stream>>>(A1, Wt2, biasF+2048, A0, distH, condF, nidx, 2048);
  gemm_bt_k  <<<512, 256, 0, stream>>>(A0, Wt3, biasF+3072, A1);
  gemm_out_k <<<128, 256, 0, stream>>>(A1, Wt_o, Pp);
  gather_k   <<<2560, 256, 0, stream>>>(Pp, tensF, biasF, nidx, d_out, flag);
}

// Round 13
// 203.326 us; speedup vs baseline: 2.1822x; 1.0116x over previous
//
// MongeGapTransport: KNN gather + 5-layer MLP pushforward, bf16 I/O (confirmed).
// R28: R26 (205.7us, PASSED) + LDS XOR-swizzle ONLY. R27 bundled swizzle +
// work-stealing and the container died twice; the steal loop (new spin/atomic
// shape under graph replay) is the prime suspect, so it's dropped. This round
// isolates the counter-grounded fix: SQ_LDS_BANK_CONFLICT=7.26M measured on
// mega_k; [row][32]-u16 tiles put a wave's ds_read_b128 into 2/8 bank-groups.
// Fix (rule #21): gl2lds dest stays linear; pre-swizzle the per-lane GLOBAL
// source col-group (q -> q^(row&3)) and XOR identically on reads. Applied to
// gemm_bt_body / gram_tile(fl=1) / gemm_out_body. All else byte-identical R26.
#include <hip/hip_runtime.h>
#include <hip/hip_fp16.h>
#include <stdint.h>

typedef unsigned short u16;
typedef unsigned int   u32;
typedef unsigned long long u64;
typedef short v8bf __attribute__((ext_vector_type(8)));
typedef float v4f  __attribute__((ext_vector_type(4)));
typedef u16   v8u  __attribute__((ext_vector_type(8)));

#define NPTS 4096
#define DF   128
#define DR   64
#define HID  1024
#define KNN  10
#define DIN  192
#define NB   512   // mega grid size (2 blocks/CU on 256 CUs)
#define PREP_UNITS 5507

#define AS1 __attribute__((address_space(1)))
#define AS3 __attribute__((address_space(3)))

__device__ __forceinline__ float bf2f(u16 b){ return __uint_as_float(((unsigned)b)<<16); }
__device__ __forceinline__ u16 f2bf(float f){
  unsigned u = __float_as_uint(f);
  unsigned r = 0x7fffu + ((u>>16)&1u);
  return (u16)((u + r)>>16);
}
__device__ __forceinline__ u16 f2h(float f){
  __half h = __float2half(f);           // RN, monotone
  return __half_as_ushort(h);
}
__device__ __forceinline__ float softplus_f(float x){
  return x>15.f ? x : __logf(1.f + __expf(x));
}
__device__ __forceinline__ float rdv(const void* p, long j, int fl){
  return fl ? bf2f(((const u16*)p)[j]) : ((const float*)p)[j];
}
__device__ __forceinline__ void gl2lds16(const u16* g, u16* l){
  __builtin_amdgcn_global_load_lds((const AS1 unsigned int*)g, (AS3 unsigned int*)l, 16, 0, 0);
}

// ---------- workspace layout ----------
constexpr size_t OFF_BAR   = 0;      // 2x u32 barrier (cnt, rel) -- memset to 0
constexpr size_t OFF_FLAG  = 128;    // dtype flag (fallback path)
constexpr size_t OFF_SQ    = 256;
constexpr size_t OFF_NIDX  = OFF_SQ    + 16384;
constexpr size_t OFF_BIAS  = OFF_NIDX  + 163840;
constexpr size_t OFF_CONDF = OFF_BIAS  + 16640;
constexpr size_t OFF_TENSF = OFF_CONDF + 2097152;
constexpr size_t OFF_WTIN  = OFF_TENSF + 1048576;
constexpr size_t OFF_WT1   = OFF_WTIN  + 393216;
constexpr size_t OFF_WT2   = OFF_WT1   + 2097152;
constexpr size_t OFF_WT3   = OFF_WT2   + 2097152;
constexpr size_t OFF_WTO   = OFF_WT3   + 2097152;
constexpr size_t OFF_DIST  = OFF_WTO   + 131072;
constexpr size_t OFF_X     = OFF_DIST  + 33554432;   // fp16 dist
constexpr size_t OFF_A0    = OFF_X     + 1572864;
constexpr size_t OFF_A1    = OFF_A0    + 8388608;
constexpr size_t OFF_P     = OFF_A1    + 8388608;    // 4 x 1MB partials

// ---------- hand-rolled epoch grid barrier (device-scope, R25/R26-proven) ----------
__device__ __forceinline__ void gbar(u32* cnt, u32* rel, u32 e){
  __syncthreads();
  if(threadIdx.x == 0){
    __threadfence();
    u32 a = __hip_atomic_fetch_add(cnt, 1u, __ATOMIC_ACQ_REL, __HIP_MEMORY_SCOPE_AGENT);
    if(a == e*NB + (NB-1)){
      __hip_atomic_store(rel, e+1u, __ATOMIC_RELEASE, __HIP_MEMORY_SCOPE_AGENT);
    } else {
      while(__hip_atomic_load(rel, __ATOMIC_ACQUIRE, __HIP_MEMORY_SCOPE_AGENT) <= e)
        __builtin_amdgcn_s_sleep(2);
    }
    __threadfence();
  }
  __syncthreads();
}

// ---------- per-block dtype detect ----------
__device__ __forceinline__ int detect_fl(const void* cond, u16* SM){
  const u16* c = (const u16*)cond;
  int tid = threadIdx.x, n = 0;
  for(int i=tid; i<8192; i+=256){
    u16 v = c[2*i];
    int e = (v>>7)&0xff;
    n += (e>=96 && e<=158);
  }
  int* cnt = (int*)SM;
  cnt[tid] = n; __syncthreads();
  for(int s=128; s>0; s>>=1){ if(tid<s) cnt[tid]+=cnt[tid+s]; __syncthreads(); }
  int fl = (cnt[0] > 4915) ? 1 : 0;
  __syncthreads();
  return fl;
}

// ---------- vec8 convert: dst[0..8) = fp32(src[j0..j0+8)) ----------
__device__ __forceinline__ void cvt8(float* dst, const void* src, long j0, int fl){
  if(fl){
    v8u h = *(const v8u*)&((const u16*)src)[j0];
    float4 a, b;
    a.x=bf2f(h[0]); a.y=bf2f(h[1]); a.z=bf2f(h[2]); a.w=bf2f(h[3]);
    b.x=bf2f(h[4]); b.y=bf2f(h[5]); b.z=bf2f(h[6]); b.w=bf2f(h[7]);
    *(float4*)dst = a; *(float4*)(dst+4) = b;
  } else {
    *(float4*)dst     = *(const float4*)&((const float*)src)[j0];
    *(float4*)(dst+4) = *(const float4*)&((const float*)src)[j0+4];
  }
}

// ---------- prep unit (vectorized; unit id u in [0,5507)) ----------
__device__ __forceinline__ void prep_unit(int u, int tid, int fl,
    const void* cond, const void* tens,
    const void* Wi, const void* W1, const void* W2, const void* W3, const void* Wo,
    const void* bi, const void* b1, const void* b2, const void* b3, const void* bo,
    float* condF, float* tensF, float* biasF,
    u16* Oi, u16* O1, u16* O2, u16* O3, u16* Oo,
    float* sq, u16* X, u16* SM){
  if(u < 387){
    int v = u*256 + tid;
    if(v < 65536){ cvt8(condF + (size_t)v*8, cond, (long)v*8, fl); }
    else if(v < 98304){ int w = v - 65536; cvt8(tensF + (size_t)w*8, tens, (long)w*8, fl); }
    else if(v < 98824){
      int j = (v - 98304)*8;
      const void* src; int off;
      if(j < 1024){ src=bi; off=j; }
      else if(j < 2048){ src=b1; off=j-1024; }
      else if(j < 3072){ src=b2; off=j-2048; }
      else if(j < 4096){ src=b3; off=j-3072; }
      else             { src=bo; off=j-4096; }
      cvt8(biasF + j, src, off, fl);
    }
  } else if(u < 3715){
    u16 (*tile)[33] = (u16(*)[33])SM;
    int b = u - 387;
    const void* in; u16* out; int R, C, bx, by;
    if(b < 192)      {              in=Wi; out=Oi; R=192;  C=1024; bx=b&31; by=b>>5; }
    else if(b < 1216){ b -= 192;    in=W1; out=O1; R=1024; C=1024; bx=b&31; by=b>>5; }
    else if(b < 2240){ b -= 1216;   in=W2; out=O2; R=1024; C=1024; bx=b&31; by=b>>5; }
    else if(b < 3264){ b -= 2240;   in=W3; out=O3; R=1024; C=1024; bx=b&31; by=b>>5; }
    else             { b -= 3264;   in=Wo; out=Oo; R=1024; C=64;   bx=b&1;  by=b>>1; }
    int gx = bx*32, gy = by*32;
    int tx = tid&31, ty = tid>>5;
    #pragma unroll
    for(int r=ty; r<32; r+=8){
      size_t idx = (size_t)(gy+r)*C + gx + tx;
      tile[r][tx] = fl ? ((const u16*)in)[idx] : f2bf(((const float*)in)[idx]);
    }
    __syncthreads();
    #pragma unroll
    for(int r=ty; r<32; r+=8) out[(size_t)(gx+r)*R + gy + tx] = tile[tx][r];
  } else if(u < 4739){
    int b = u - 3715;
    int row = b*4 + (tid>>6), lane = tid&63;
    float a = rdv(cond, (long)row*DF + lane, fl);
    float c2 = rdv(cond, (long)row*DF + lane + 64, fl);
    double s = (double)a*a + (double)c2*c2;
    #pragma unroll
    for(int off=32; off>0; off>>=1) s += __shfl_down(s, off, 64);
    if(lane==0) sq[row] = (float)s;
  } else {
    int c = (u-4739)*256 + tid;
    int j = c/48;
    int off = (c - j*48)*4;
    ushort4 o;
    if(fl){
      o = (off < DF) ? *(const ushort4*)&((const u16*)cond)[(size_t)j*DF + off]
                     : *(const ushort4*)&((const u16*)tens)[(size_t)j*DR + off - DF];
    } else if(off < DF){
      o.x = f2bf(((const float*)cond)[(size_t)j*DF + off + 0]);
      o.y = f2bf(((const float*)cond)[(size_t)j*DF + off + 1]);
      o.z = f2bf(((const float*)cond)[(size_t)j*DF + off + 2]);
      o.w = f2bf(((const float*)cond)[(size_t)j*DF + off + 3]);
    }else{
      int t2 = off - DF;
      o.x = f2bf(((const float*)tens)[(size_t)j*DR + t2 + 0]);
      o.y = f2bf(((const float*)tens)[(size_t)j*DR + t2 + 1]);
      o.z = f2bf(((const float*)tens)[(size_t)j*DR + t2 + 2]);
      o.w = f2bf(((const float*)tens)[(size_t)j*DR + t2 + 3]);
    }
    *(ushort4*)&X[(size_t)j*DIN + off] = o;
  }
}

// ---------- hidden GEMM body: 128x64 tile, BK=64, XOR-swizzled LDS ----------
// LDS[r][qp] holds logical (r, qp^(r&3)); gl2lds dest linear, SOURCE pre-swizzled.
__device__ __forceinline__ void gemm_bt_body(const u16* __restrict__ A,
    const u16* __restrict__ Bt, const float* __restrict__ bias, u16* __restrict__ C,
    int Nc, int Kc, int bid, u16* As, u16* Bs){
  const int xcd = bid&7, slot = bid>>3;
  const int bm = (xcd*4 + (slot>>4)) * 128;
  const int bn = (slot&15) * 64;
  const int tid = threadIdx.x, lane = tid&63, wave = tid>>6;
  const int wm = (wave&1)*64, wn = (wave>>1)*32;
  int c0 = wave*128 + lane, c1 = c0 + 64;
  int r0 = c0>>2, q0 = c0&3, r1 = c1>>2;     // q1==q0, r1&3==r0&3
  int cb = wave*64 + lane, rb = cb>>2, qb = cb&3;
  const u16* pA0 = A  + (size_t)(bm+r0)*Kc + (q0^(r0&3))*8;
  const u16* pA1 = A  + (size_t)(bm+r1)*Kc + (q0^(r0&3))*8;
  const u16* pB  = Bt + (size_t)(bn+rb)*Kc + (qb^(rb&3))*8;
  u16* lA0 = &As[wave*1024];
  u16* lA1 = &As[wave*1024 + 512];
  u16* lB  = &Bs[wave*512];
  const int m16 = lane&15, q = lane>>4;
  v4f acc[4][2] = {};
  for(int kb=0; kb<Kc; kb+=64){
    gl2lds16(pA0 + kb, lA0);
    gl2lds16(pA1 + kb, lA1);
    gl2lds16(pB  + kb, lB);
    gl2lds16(pA0 + kb + 32, lA0 + 4096);
    gl2lds16(pA1 + kb + 32, lA1 + 4096);
    gl2lds16(pB  + kb + 32, lB + 2048);
    __syncthreads();
    #pragma unroll
    for(int kk=0;kk<2;kk++){
      v8bf a[4], b[2];
      #pragma unroll
      for(int x=0;x<4;x++){
        int row = wm + x*16 + m16;
        a[x] = *(const v8bf*)&As[kk*4096 + row*32 + (q^(row&3))*8];
      }
      #pragma unroll
      for(int x=0;x<2;x++){
        int row = wn + x*16 + m16;
        b[x] = *(const v8bf*)&Bs[kk*2048 + row*32 + (q^(row&3))*8];
      }
      #pragma unroll
      for(int mi=0;mi<4;mi++)
        #pragma unroll
        for(int ni=0;ni<2;ni++)
          acc[mi][ni] = __builtin_amdgcn_mfma_f32_16x16x32_bf16(a[mi], b[ni], acc[mi][ni], 0,0,0);
    }
    __syncthreads();
  }
  const int col16 = lane&15, rowq = lane>>4;
  #pragma unroll
  for(int mi=0;mi<4;mi++){
    #pragma unroll
    for(int ni=0;ni<2;ni++){
      int cn = bn + wn + ni*16 + col16;
      float bi = bias[cn];
      #pragma unroll
      for(int r=0;r<4;r++){
        int rw = bm + wm + mi*16 + rowq*4 + r;
        float v = softplus_f(acc[mi][ni][r] + bi);
        C[(size_t)rw*Nc + cn] = f2bf(v);
      }
    }
  }
}

// ---------- knn 1-row body (R23-proven; fallback path) ----------
__device__ __forceinline__ void knn_body(const u16* __restrict__ distH,
    const float* __restrict__ condF, int* __restrict__ nidx, int row,
    float* __restrict__ af, int* __restrict__ cand, u64* __restrict__ keys){
  const int lane = threadIdx.x&63;
  af[lane]    = condF[(size_t)row*DF + lane];
  af[lane+64] = condF[(size_t)row*DF + lane + 64];
  const v8u* drow = (const v8u*)(distH + (size_t)row*NPTS);
  v8u vals[8];
  #pragma unroll
  for(int k=0;k<8;k++) vals[k] = drow[lane + k*64];
  u32 mx = 0;
  #pragma unroll
  for(int k=0;k<8;k++)
    #pragma unroll
    for(int e=0;e<8;e++){ u32 v = vals[k][e]; mx = v>mx ? v : mx; }
  #pragma unroll
  for(int off=32; off>0; off>>=1){
    u32 o = (u32)__shfl_down((int)mx, off, 64); mx = o>mx ? o : mx;
  }
  mx = (u32)__shfl((int)mx, 0, 64);
  u32 hi = mx+1, lo = 0;
  for(int it=0; it<17; ++it){
    u32 mid = (lo+hi)>>1;
    int c = 0;
    #pragma unroll
    for(int k=0;k<8;k++)
      #pragma unroll
      for(int e=0;e<8;e++)
        c += (int)__popcll(__ballot((u32)vals[k][e] < mid));
    if(c >= 16){ hi = mid; if(c <= 64) break; }
    else lo = mid;
  }
  const u32 t = hi;
  const u64 below = (1ull<<lane) - 1ull;
  int base = 0;
  #pragma unroll
  for(int k=0;k<8;k++)
    #pragma unroll
    for(int e=0;e<8;e++){
      bool p = (u32)vals[k][e] < t;
      u64 m = __ballot(p);
      if(p){
        int off = base + (int)__popcll(m & below);
        if(off < 64) cand[off] = (lane + k*64)*8 + e;
      }
      base += (int)__popcll(m);
    }
  int cnt = base > 64 ? 64 : base;
  u64 mykey = ~0ULL; int myj = -1;
  if(lane < cnt){
    int j = cand[lane];
    const float4* bp4 = (const float4*)(condF + (size_t)j*DF);
    double s = 0.0;
    #pragma unroll
    for(int v4i=0; v4i<32; v4i++){
      float4 bv = bp4[v4i];
      double d0 = (double)af[v4i*4+0]-(double)bv.x;
      double d1 = (double)af[v4i*4+1]-(double)bv.y;
      double d2 = (double)af[v4i*4+2]-(double)bv.z;
      double d3 = (double)af[v4i*4+3]-(double)bv.w;
      s += d0*d0 + d1*d1 + d2*d2 + d3*d3;
    }
    u64 bits = (u64)__double_as_longlong(s);
    mykey = (bits & ~0xFFFULL) | (u32)j;
    myj = j;
  }
  keys[lane] = mykey;
  if(lane < cnt){
    int rank = 0;
    for(int c2=0;c2<cnt;c2++) rank += (keys[c2] < mykey);
    if(rank < KNN) nidx[row*KNN + rank] = myj;
  }
}

// ---------- knn 2-rows-per-wave ILP body (R26-proven) ----------
__device__ __forceinline__ void knn_body2(const u16* __restrict__ distH,
    const float* __restrict__ condF, int* __restrict__ nidx, int row0, int row1,
    float* af0, float* af1, int* can0, int* can1, u64* key0, u64* key1){
  const int lane = threadIdx.x&63;
  af0[lane]    = condF[(size_t)row0*DF + lane];
  af0[lane+64] = condF[(size_t)row0*DF + lane + 64];
  af1[lane]    = condF[(size_t)row1*DF + lane];
  af1[lane+64] = condF[(size_t)row1*DF + lane + 64];
  const v8u* dr0 = (const v8u*)(distH + (size_t)row0*NPTS);
  const v8u* dr1 = (const v8u*)(distH + (size_t)row1*NPTS);
  v8u v0[8], v1[8];
  #pragma unroll
  for(int k=0;k<8;k++){ v0[k] = dr0[lane + k*64]; v1[k] = dr1[lane + k*64]; }
  u32 m0 = 0, m1 = 0;
  #pragma unroll
  for(int k=0;k<8;k++)
    #pragma unroll
    for(int e=0;e<8;e++){
      u32 a = v0[k][e]; m0 = a>m0 ? a : m0;
      u32 b = v1[k][e]; m1 = b>m1 ? b : m1;
    }
  #pragma unroll
  for(int off=32; off>0; off>>=1){
    u32 a = (u32)__shfl_down((int)m0, off, 64); m0 = a>m0 ? a : m0;
    u32 b = (u32)__shfl_down((int)m1, off, 64); m1 = b>m1 ? b : m1;
  }
  m0 = (u32)__shfl((int)m0, 0, 64);
  m1 = (u32)__shfl((int)m1, 0, 64);
  u32 hi0 = m0+1, lo0 = 0, hi1 = m1+1, lo1 = 0;
  bool done0 = false, done1 = false;
  for(int it=0; it<17 && !(done0 && done1); ++it){
    u32 mid0 = (lo0+hi0)>>1, mid1 = (lo1+hi1)>>1;
    int c0 = 0, c1 = 0;
    #pragma unroll
    for(int k=0;k<8;k++)
      #pragma unroll
      for(int e=0;e<8;e++){
        c0 += ((u32)v0[k][e] < mid0);
        c1 += ((u32)v1[k][e] < mid1);
      }
    #pragma unroll
    for(int off=32; off>0; off>>=1){
      c0 += __shfl_down(c0, off, 64);
      c1 += __shfl_down(c1, off, 64);
    }
    c0 = __shfl(c0, 0, 64);
    c1 = __shfl(c1, 0, 64);
    if(!done0){ if(c0 >= 16){ hi0 = mid0; if(c0 <= 64) done0 = true; } else lo0 = mid0; }
    if(!done1){ if(c1 >= 16){ hi1 = mid1; if(c1 <= 64) done1 = true; } else lo1 = mid1; }
  }
  const u32 t0 = hi0, t1 = hi1;
  const u64 below = (1ull<<lane) - 1ull;
  int base0 = 0, base1 = 0;
  #pragma unroll
  for(int k=0;k<8;k++)
    #pragma unroll
    for(int e=0;e<8;e++){
      bool p0 = (u32)v0[k][e] < t0;
      u64 q0 = __ballot(p0);
      if(p0){
        int off = base0 + (int)__popcll(q0 & below);
        if(off < 64) can0[off] = (lane + k*64)*8 + e;
      }
      base0 += (int)__popcll(q0);
      bool p1 = (u32)v1[k][e] < t1;
      u64 q1 = __ballot(p1);
      if(p1){
        int off = base1 + (int)__popcll(q1 & below);
        if(off < 64) can1[off] = (lane + k*64)*8 + e;
      }
      base1 += (int)__popcll(q1);
    }
  int cnt0 = base0 > 64 ? 64 : base0;
  int cnt1 = base1 > 64 ? 64 : base1;
  int j0 = (lane < cnt0) ? can0[lane] : 0;
  int j1 = (lane < cnt1) ? can1[lane] : 0;
  const float4* p0 = (const float4*)(condF + (size_t)j0*DF);
  const float4* p1 = (const float4*)(condF + (size_t)j1*DF);
  double s0 = 0.0, s1 = 0.0;
  #pragma unroll
  for(int v4i=0; v4i<32; v4i++){
    float4 a = p0[v4i], b = p1[v4i];
    double d0 = (double)af0[v4i*4+0]-(double)a.x;
    double d1 = (double)af0[v4i*4+1]-(double)a.y;
    double d2 = (double)af0[v4i*4+2]-(double)a.z;
    double d3 = (double)af0[v4i*4+3]-(double)a.w;
    s0 += d0*d0 + d1*d1 + d2*d2 + d3*d3;
    double e0 = (double)af1[v4i*4+0]-(double)b.x;
    double e1 = (double)af1[v4i*4+1]-(double)b.y;
    double e2 = (double)af1[v4i*4+2]-(double)b.z;
    double e3 = (double)af1[v4i*4+3]-(double)b.w;
    s1 += e0*e0 + e1*e1 + e2*e2 + e3*e3;
  }
  u64 mk0 = ~0ULL, mk1 = ~0ULL;
  if(lane < cnt0) mk0 = ((u64)__double_as_longlong(s0) & ~0xFFFULL) | (u32)j0;
  if(lane < cnt1) mk1 = ((u64)__double_as_longlong(s1) & ~0xFFFULL) | (u32)j1;
  key0[lane] = mk0;
  key1[lane] = mk1;
  if(lane < cnt0){
    int rank = 0;
    for(int c2=0;c2<cnt0;c2++) rank += (key0[c2] < mk0);
    if(rank < KNN) nidx[row0*KNN + rank] = j0;
  }
  if(lane < cnt1){
    int rank = 0;
    for(int c2=0;c2<cnt1;c2++) rank += (key1[c2] < mk1);
    if(rank < KNN) nidx[row1*KNN + rank] = j1;
  }
}

// ---------- gram tile: fl=1 gl2lds + XOR-swizzled tiles; fl=0 hi/lo (unchanged) ----------
__device__ __forceinline__ void gram_tile(int gb, int fl,
    const u16* __restrict__ condB, const float* __restrict__ condF,
    const float* __restrict__ sq, u16* __restrict__ distH, u16* SM){
  const int bm = (gb&31)*128, bn = (gb>>5)*128;
  const int tid = threadIdx.x, lane = tid&63, wave = tid>>6;
  const int wm = (wave&1)*64, wn = (wave>>1)*64;
  const int m16 = lane&15, q = lane>>4;
  v4f acc[4][4] = {};
  if(fl){
    const int srow = wave*32 + (lane>>2);
    const int scol = ((lane&3)^(srow&3))*8;            // pre-swizzled source
    const u16* gA = condB + (size_t)(bm+srow)*DF + scol;
    const u16* gB = condB + (size_t)(bn+srow)*DF + scol;
    u16* lA = &SM[wave*1024];
    u16* lB = &SM[4096 + wave*1024];
    for(int kb=0; kb<DF; kb+=32){
      gl2lds16(gA + kb,                 lA);
      gl2lds16(gA + kb + (size_t)16*DF, lA + 512);
      gl2lds16(gB + kb,                 lB);
      gl2lds16(gB + kb + (size_t)16*DF, lB + 512);
      __syncthreads();
      v8bf a[4], b[4];
      #pragma unroll
      for(int x=0;x<4;x++){
        int ra = wm + x*16 + m16;
        int rb2 = wn + x*16 + m16;
        a[x] = *(const v8bf*)&SM[ra*32 + (q^(ra&3))*8];
        b[x] = *(const v8bf*)&SM[4096 + rb2*32 + (q^(rb2&3))*8];
      }
      #pragma unroll
      for(int mi=0;mi<4;mi++)
        #pragma unroll
        for(int ni=0;ni<4;ni++)
          acc[mi][ni] = __builtin_amdgcn_mfma_f32_16x16x32_bf16(a[mi], b[ni], acc[mi][ni], 0,0,0);
      __syncthreads();
    }
  } else {
    u16* Ahi = SM;
    u16* Alo = SM + 5120;
    u16* Bhi = SM + 10240;
    u16* Blo = SM + 15360;
    for(int kb=0; kb<DF; kb+=32){
      #pragma unroll
      for(int t=0;t<4;t++){
        int ch = tid + t*256;
        int r = ch>>3, c = (ch&7)*4;
        float4 av = *(const float4*)&condF[(size_t)(bm+r)*DF + kb + c];
        float4 bv = *(const float4*)&condF[(size_t)(bn+r)*DF + kb + c];
        ushort4 ah, bh, al, bl;
        ah.x=f2bf(av.x); ah.y=f2bf(av.y); ah.z=f2bf(av.z); ah.w=f2bf(av.w);
        bh.x=f2bf(bv.x); bh.y=f2bf(bv.y); bh.z=f2bf(bv.z); bh.w=f2bf(bv.w);
        al.x=f2bf(av.x-bf2f(ah.x)); al.y=f2bf(av.y-bf2f(ah.y));
        al.z=f2bf(av.z-bf2f(ah.z)); al.w=f2bf(av.w-bf2f(ah.w));
        bl.x=f2bf(bv.x-bf2f(bh.x)); bl.y=f2bf(bv.y-bf2f(bh.y));
        bl.z=f2bf(bv.z-bf2f(bh.z)); bl.w=f2bf(bv.w-bf2f(bh.w));
        *(ushort4*)&Ahi[r*40+c] = ah; *(ushort4*)&Bhi[r*40+c] = bh;
        *(ushort4*)&Alo[r*40+c] = al; *(ushort4*)&Blo[r*40+c] = bl;
      }
      __syncthreads();
      v8bf ahf[4], bhf[4], alf[4], blf[4];
      #pragma unroll
      for(int x=0;x<4;x++){
        ahf[x] = *(const v8bf*)&Ahi[(wm + x*16 + m16)*40 + q*8];
        bhf[x] = *(const v8bf*)&Bhi[(wn + x*16 + m16)*40 + q*8];
        alf[x] = *(const v8bf*)&Alo[(wm + x*16 + m16)*40 + q*8];
        blf[x] = *(const v8bf*)&Blo[(wn + x*16 + m16)*40 + q*8];
      }
      #pragma unroll
      for(int mi=0;mi<4;mi++)
        #pragma unroll
        for(int ni=0;ni<4;ni++){
          acc[mi][ni] = __builtin_amdgcn_mfma_f32_16x16x32_bf16(alf[mi], bhf[ni], acc[mi][ni], 0,0,0);
          acc[mi][ni] = __builtin_amdgcn_mfma_f32_16x16x32_bf16(ahf[mi], blf[ni], acc[mi][ni], 0,0,0);
          acc[mi][ni] = __builtin_amdgcn_mfma_f32_16x16x32_bf16(ahf[mi], bhf[ni], acc[mi][ni], 0,0,0);
        }
      __syncthreads();
    }
  }
  const int col16 = lane&15, rowq = lane>>4;
  #pragma unroll
  for(int mi=0;mi<4;mi++){
    #pragma unroll
    for(int ni=0;ni<4;ni++){
      int cj = bn + wn + ni*16 + col16;
      float sqj = sq[cj];
      #pragma unroll
      for(int r=0;r<4;r++){
        int ri = bm + wm + mi*16 + rowq*4 + r;
        float d2 = (sq[ri] + sqj) - 2.0f*acc[mi][ni][r];
        distH[(size_t)ri*NPTS + cj] = f2h(fmaxf(d2, 0.f));
      }
    }
  }
}

// ---------- final layer split-K body, XOR-swizzled (obid in [0,128)) ----------
__device__ __forceinline__ void gemm_out_body(int obid, const u16* __restrict__ A,
    const u16* __restrict__ Bt, float* __restrict__ Pp, u16* As, u16* Bs){
  const int bm = (obid>>2)*128;
  const int k0 = (obid&3)*256;
  float* P = Pp + (size_t)(obid&3)*262144;
  const int tid = threadIdx.x, lane = tid&63, wave = tid>>6;
  const int wm = wave*32;
  int c0 = wave*128 + lane, c1 = c0 + 64;
  int ra0 = c0>>2, qa0 = c0&3, ra1 = c1>>2;   // qa1==qa0, ra1&3==ra0&3
  int cb = wave*64 + lane;
  int rb = cb>>2, qb = cb&3;
  const u16* pA0 = A  + (size_t)(bm+ra0)*HID + (qa0^(ra0&3))*8;
  const u16* pA1 = A  + (size_t)(bm+ra1)*HID + (qa0^(ra0&3))*8;
  const u16* pB  = Bt + (size_t)rb*HID + (qb^(rb&3))*8;
  u16* lA0 = &As[(wave*128     )*8];
  u16* lA1 = &As[(wave*128 + 64)*8];
  u16* lB  = &Bs[(wave*64      )*8];
  const int m16 = lane&15, q = lane>>4;
  v4f acc[2][4] = {};
  for(int kb=k0; kb<k0+256; kb+=32){
    gl2lds16(pA0 + kb, lA0);
    gl2lds16(pA1 + kb, lA1);
    gl2lds16(pB  + kb, lB);
    __syncthreads();
    v8bf a[2], b[4];
    {
      int r0r = wm + m16, r1r = wm + 16 + m16;
      a[0] = *(const v8bf*)&As[r0r*32 + (q^(r0r&3))*8];
      a[1] = *(const v8bf*)&As[r1r*32 + (q^(r1r&3))*8];
    }
    #pragma unroll
    for(int x=0;x<4;x++){
      int row = x*16 + m16;
      b[x] = *(const v8bf*)&Bs[row*32 + (q^(row&3))*8];
    }
    #pragma unroll
    for(int mi=0;mi<2;mi++)
      #pragma unroll
      for(int ni=0;ni<4;ni++)
        acc[mi][ni] = __builtin_amdgcn_mfma_f32_16x16x32_bf16(a[mi], b[ni], acc[mi][ni], 0,0,0);
    __syncthreads();
  }
  const int col16 = lane&15, rowq = lane>>4;
  #pragma unroll
  for(int mi=0;mi<2;mi++){
    #pragma unroll
    for(int ni=0;ni<4;ni++){
      int cn = ni*16 + col16;
      #pragma unroll
      for(int r=0;r<4;r++){
        int rw = bm + wm + mi*16 + rowq*4 + r;
        P[(size_t)rw*DR + cn] = acc[mi][ni][r];
      }
    }
  }
}

// ---------- gather unit ----------
__device__ __forceinline__ void gather_unit(int e, int fl,
    const float* Pp, const float* tensF, const float* biasF,
    const int* nidx, void* outv){
  int m = e>>4;
  int c = (e&15)*4;
  int j = nidx[m] & (NPTS-1);
  size_t rc = (size_t)j*DR + c;
  float4 t  = *(const float4*)&tensF[rc];
  float4 b  = *(const float4*)&biasF[4096 + c];
  float4 p0 = *(const float4*)&Pp[rc];
  float4 p1 = *(const float4*)&Pp[262144 + rc];
  float4 p2 = *(const float4*)&Pp[524288 + rc];
  float4 p3 = *(const float4*)&Pp[786432 + rc];
  float4 v;
  v.x = t.x - (b.x + ((p0.x+p1.x)+(p2.x+p3.x)));
  v.y = t.y - (b.y + ((p0.y+p1.y)+(p2.y+p3.y)));
  v.z = t.z - (b.z + ((p0.z+p1.z)+(p2.z+p3.z)));
  v.w = t.w - (b.w + ((p0.w+p1.w)+(p2.w+p3.w)));
  if(fl){
    ushort4 o; o.x=f2bf(v.x); o.y=f2bf(v.y); o.z=f2bf(v.z); o.w=f2bf(v.w);
    *(ushort4*)&((u16*)outv)[(size_t)m*DR + c] = o;
  }else{
    *(float4*)&((float*)outv)[(size_t)m*DR + c] = v;
  }
}

// ---------- THE mega-kernel (R26 structure; plain launch; grid barrier) ----------
__global__ void __launch_bounds__(256,2) mega_k(
    const void* cond, const void* tens,
    const void* Wi, const void* W1w, const void* W2w, const void* W3w, const void* Wow,
    const void* bi, const void* b1, const void* b2, const void* b3, const void* bo,
    char* ws, void* outv){
  __shared__ __align__(16) u16 SM[20480];   // 40KB -> 2 blocks/CU
  const int bid = blockIdx.x, tid = threadIdx.x;

  u32*   bcnt  = (u32*)  (ws + OFF_BAR);
  u32*   brel  = (u32*)  (ws + OFF_BAR + 8);
  float* sqv   = (float*)(ws + OFF_SQ);
  int*   nidx  = (int*)  (ws + OFF_NIDX);
  float* biasF = (float*)(ws + OFF_BIAS);
  float* condF = (float*)(ws + OFF_CONDF);
  float* tensF = (float*)(ws + OFF_TENSF);
  u16*   Wt_in = (u16*)  (ws + OFF_WTIN);
  u16*   Wt1   = (u16*)  (ws + OFF_WT1);
  u16*   Wt2   = (u16*)  (ws + OFF_WT2);
  u16*   Wt3   = (u16*)  (ws + OFF_WT3);
  u16*   Wt_o  = (u16*)  (ws + OFF_WTO);
  u16*   distH = (u16*)  (ws + OFF_DIST);
  u16*   X     = (u16*)  (ws + OFF_X);
  u16*   A0    = (u16*)  (ws + OFF_A0);
  u16*   A1    = (u16*)  (ws + OFF_A1);
  float* Pp    = (float*)(ws + OFF_P);

  const int fl = detect_fl(cond, SM);

  // ---- P0: prep, grid-strided ----
  for(int u=bid; u<PREP_UNITS; u+=NB){
    prep_unit(u, tid, fl, cond, tens, Wi, W1w, W2w, W3w, Wow, bi, b1, b2, b3, bo,
              condF, tensF, biasF, Wt_in, Wt1, Wt2, Wt3, Wt_o, sqv, X, SM);
    __syncthreads();
  }
  gbar(bcnt, brel, 0);

  // ---- P1: gemm1 (1 tile) then gram (2 tiles grid-strided) ----
  gemm_bt_body(X, Wt_in, biasF, A0, HID, DIN, bid, SM, SM+8192);
  __syncthreads();
  for(int gb=bid; gb<1024; gb+=NB){
    gram_tile(gb, fl, (const u16*)cond, condF, sqv, distH, SM);
    __syncthreads();
  }
  gbar(bcnt, brel, 1);

  // knn LDS slices: 8 slots (4 waves x 2 rows)
  const int wv = tid>>6;
  float* kaf0 = (float*)SM + (wv*2+0)*128;
  float* kaf1 = (float*)SM + (wv*2+1)*128;               // 0..4096B
  int*   kc0  = (int*)((char*)SM + 4096) + (wv*2+0)*64;
  int*   kc1  = (int*)((char*)SM + 4096) + (wv*2+1)*64;  // 4096..6144B
  u64*   kk0  = (u64*)((char*)SM + 8192) + (wv*2+0)*64;
  u64*   kk1  = (u64*)((char*)SM + 8192) + (wv*2+1)*64;  // 8192..12288B

  // ---- P2: gemm2 (blocks 0-255, 2 tiles) || knn rows 0..2047 (2/wave ILP) ----
  if(bid < 256){
    gemm_bt_body(A0, Wt1, biasF+1024, A1, HID, HID, bid,     SM, SM+8192);
    __syncthreads();
    gemm_bt_body(A0, Wt1, biasF+1024, A1, HID, HID, bid+256, SM, SM+8192);
  } else {
    int r0 = (bid-256)*4 + wv;
    knn_body2(distH, condF, nidx, r0, r0 + 1024, kaf0, kaf1, kc0, kc1, kk0, kk1);
  }
  gbar(bcnt, brel, 2);

  // ---- P3: gemm3 || knn rows 2048..4095 ----
  if(bid < 256){
    gemm_bt_body(A1, Wt2, biasF+2048, A0, HID, HID, bid,     SM, SM+8192);
    __syncthreads();
    gemm_bt_body(A1, Wt2, biasF+2048, A0, HID, HID, bid+256, SM, SM+8192);
  } else {
    int r0 = 2048 + (bid-256)*4 + wv;
    knn_body2(distH, condF, nidx, r0, r0 + 1024, kaf0, kaf1, kc0, kc1, kk0, kk1);
  }
  gbar(bcnt, brel, 3);

  // ---- P4: gemm4, full 512 blocks (1 tile each) ----
  gemm_bt_body(A0, Wt3, biasF+3072, A1, HID, HID, bid, SM, SM+8192);
  gbar(bcnt, brel, 4);

  // ---- P5: gemm_out (blocks 0-127, split-K=4) ----
  if(bid < 128){
    gemm_out_body(bid, A1, Wt_o, Pp, SM, SM+8192);
  }
  gbar(bcnt, brel, 5);

  // ---- P6: gather, grid-strided ----
  for(int u=bid; u<2560; u+=NB)
    gather_unit(u*256 + tid, fl, Pp, tensF, biasF, nidx, outv);
}

// ================= fallback path: R23-structure kernels =================
__global__ void detect_k(const u16* __restrict__ c, int* __restrict__ flag){
  __shared__ int cnt[256];
  int t = threadIdx.x, n = 0;
  for(int i=t; i<8192; i+=256){
    u16 v = c[2*i];
    int e = (v>>7)&0xff;
    n += (e>=96 && e<=158);
  }
  cnt[t] = n; __syncthreads();
  for(int s=128; s>0; s>>=1){ if(t<s) cnt[t]+=cnt[t+s]; __syncthreads(); }
  if(t==0) *flag = (cnt[0] > 4915) ? 1 : 0;
}

__global__ void prep_k(const void* cond, const void* tens,
    const void* Wi, const void* W1, const void* W2, const void* W3, const void* Wo,
    const void* bi, const void* b1, const void* b2, const void* b3, const void* bo,
    float* condF, float* tensF, float* biasF,
    u16* Oi, u16* O1, u16* O2, u16* O3, u16* Oo,
    float* sq, u16* X, const int* __restrict__ flag){
  __shared__ __align__(16) u16 SM[1056];
  prep_unit(blockIdx.x, threadIdx.x, *flag, cond, tens, Wi, W1, W2, W3, Wo,
            bi, b1, b2, b3, bo, condF, tensF, biasF, Oi, O1, O2, O3, Oo, sq, X, SM);
}

__global__ __launch_bounds__(256,2) void gram_g1_k(const u16* __restrict__ condB,
    const float* __restrict__ condF, const float* __restrict__ sq,
    u16* __restrict__ distH, const int* __restrict__ flag,
    const u16* __restrict__ X, const u16* __restrict__ Wt_in,
    const float* __restrict__ biasF, u16* __restrict__ A0){
  __shared__ __align__(16) u16 SM[20480];
  const int bid = blockIdx.x;
  if(bid < 512){
    gemm_bt_body(X, Wt_in, biasF, A0, HID, DIN, bid, SM, SM+8192);
  } else {
    gram_tile(bid-512, *flag, condB, condF, sq, distH, SM);
  }
}

__global__ __launch_bounds__(256,2) void gemm_knn_k(const u16* __restrict__ A,
    const u16* __restrict__ Bt, const float* __restrict__ bias, u16* __restrict__ C,
    const u16* __restrict__ distH, const float* __restrict__ condF,
    int* __restrict__ nidx, int rowoff){
  __shared__ __align__(16) u16 gsm[12288];
  __shared__ float af[4][DF];
  __shared__ int   cand[4][64];
  __shared__ u64   keys[4][64];
  const int bid = blockIdx.x;
  if(bid < 512){
    gemm_bt_body(A, Bt, bias, C, HID, HID, bid, gsm, gsm+8192);
  } else {
    const int wv = threadIdx.x>>6;
    knn_body(distH, condF, nidx, rowoff + (bid-512)*4 + wv, af[wv], cand[wv], keys[wv]);
  }
}

__global__ __launch_bounds__(256,2) void gemm_bt_k(const u16* __restrict__ A,
    const u16* __restrict__ Bt, const float* __restrict__ bias, u16* __restrict__ C){
  __shared__ __align__(16) u16 As[8192];
  __shared__ __align__(16) u16 Bs[4096];
  gemm_bt_body(A, Bt, bias, C, HID, HID, blockIdx.x, As, Bs);
}

__global__ __launch_bounds__(256,2) void gemm_out_k(const u16* __restrict__ A,
    const u16* __restrict__ Bt, float* __restrict__ Pp){
  __shared__ __align__(16) u16 As[4096];
  __shared__ __align__(16) u16 Bs[2048];
  gemm_out_body(blockIdx.x, A, Bt, Pp, As, Bs);
}

__global__ void gather_k(const float* __restrict__ Pp, const float* __restrict__ tensF,
                         const float* __restrict__ biasF, const int* __restrict__ nidx,
                         void* __restrict__ outv, const int* __restrict__ flag){
  gather_unit(blockIdx.x*256 + threadIdx.x, *flag, Pp, tensF, biasF, nidx, outv);
}

extern "C" void kernel_launch(void* const* d_in, const int* in_sizes, int n_in,
                              void* d_out, int out_size, void* d_ws, size_t ws_size,
                              hipStream_t stream){
  char* ws = (char*)d_ws;
  int*   flag  = (int*)  (ws + OFF_FLAG);
  float* sqv   = (float*)(ws + OFF_SQ);
  int*   nidx  = (int*)  (ws + OFF_NIDX);
  float* biasF = (float*)(ws + OFF_BIAS);
  float* condF = (float*)(ws + OFF_CONDF);
  float* tensF = (float*)(ws + OFF_TENSF);
  u16*   Wt_in = (u16*)  (ws + OFF_WTIN);
  u16*   Wt1   = (u16*)  (ws + OFF_WT1);
  u16*   Wt2   = (u16*)  (ws + OFF_WT2);
  u16*   Wt3   = (u16*)  (ws + OFF_WT3);
  u16*   Wt_o  = (u16*)  (ws + OFF_WTO);
  u16*   distH = (u16*)  (ws + OFF_DIST);
  u16*   X     = (u16*)  (ws + OFF_X);
  u16*   A0    = (u16*)  (ws + OFF_A0);
  u16*   A1    = (u16*)  (ws + OFF_A1);
  float* Pp    = (float*)(ws + OFF_P);

  // Occupancy guard: mega needs 2 blocks/CU (512 co-resident) or its grid
  // barrier would deadlock. Query once; fall back to the proven path.
  static int occ_cached = -1;
  if(occ_cached < 0){
    int occ = 0;
    if(hipOccupancyMaxActiveBlocksPerMultiprocessor(&occ, (const void*)mega_k, 256, 0)
       != hipSuccess) occ = 0;
    occ_cached = occ;
  }

  if(occ_cached >= 2){
    hipMemsetAsync(ws + OFF_BAR, 0, 64, stream);   // zero barrier words (captured)
    hipLaunchKernelGGL(mega_k, dim3(NB), dim3(256), 0, stream,
        d_in[0], d_in[1], d_in[2], d_in[4], d_in[6], d_in[8], d_in[10],
        d_in[3], d_in[5], d_in[7], d_in[9], d_in[11], ws, d_out);
    return;
  }

  // ---- fallback ----
  detect_k <<<1, 256, 0, stream>>>((const u16*)d_in[0], flag);
  prep_k   <<<PREP_UNITS, 256, 0, stream>>>(d_in[0], d_in[1],
                d_in[2], d_in[4], d_in[6], d_in[8], d_in[10],
                d_in[3], d_in[5], d_in[7], d_in[9], d_in[11],
                condF, tensF, biasF, Wt_in, Wt1, Wt2, Wt3, Wt_o, sqv, X, flag);
  gram_g1_k<<<1536, 256, 0, stream>>>((const u16*)d_in[0], condF, sqv, distH, flag,
                                      X, Wt_in, biasF, A0);
  gemm_knn_k<<<1024, 256, 0, stream>>>(A0, Wt1, biasF+1024, A1, distH, condF, nidx, 0);
  gemm_knn_k<<<1024, 256, 0, stream>>>(A1, Wt2, biasF+2048, A0, distH, condF, nidx, 2048);
  gemm_bt_k  <<<512, 256, 0, stream>>>(A0, Wt3, biasF+3072, A1);
  gemm_out_k <<<128, 256, 0, stream>>>(A1, Wt_o, Pp);
  gather_k   <<<2560, 256, 0, stream>>>(Pp, tensF, biasF, nidx, d_out, flag);
}